// Round 9
// baseline (305.545 us; speedup 1.0000x reference)
//
#include <hip/hip_runtime.h>
#include <hip/hip_bf16.h>
#include <math.h>

#define DIM    1024
#define SEQT   2048
#define NB     4
#define SCALE  0.03125f   // 1/32 = DIM^-0.5, exact power of two
#define KTOP   64
#define NT2    136        // 16*17/2 causal 128x128 tiles per batch
#define DELTA  5e-2f      // fp64-recheck window (covers split-2 score error ~45x)

typedef __attribute__((ext_vector_type(8))) short short8;   // 8 bf16 = 4 VGPR
typedef __attribute__((ext_vector_type(4))) float f32x4;    // MFMA C/D frag

// ---- bf16 RNE helpers (manual, deterministic) ------------------------------
__device__ __forceinline__ unsigned short bfr(float x) {
    unsigned u = __float_as_uint(x);
    unsigned r = (u + 0x7fffu + ((u >> 16) & 1u)) >> 16;
    return (unsigned short)r;
}
__device__ __forceinline__ float bf2f(unsigned short h) {
    return __uint_as_float(((unsigned)h) << 16);
}

// ---------------------------------------------------------------------------
// split_bf16: x -> hi = bf16(x), lo = bf16(x - hi)   (grid-stride, float4)
// ---------------------------------------------------------------------------
__global__ __launch_bounds__(256) void split_bf16(const float* __restrict__ x,
                                                  unsigned short* __restrict__ hi,
                                                  unsigned short* __restrict__ lo,
                                                  int n4) {
    const int stride = gridDim.x * 256;
    for (int idx = blockIdx.x * 256 + threadIdx.x; idx < n4; idx += stride) {
        float4 v = reinterpret_cast<const float4*>(x)[idx];
        ushort4 h, l;
        h.x = bfr(v.x); l.x = bfr(v.x - bf2f(h.x));
        h.y = bfr(v.y); l.y = bfr(v.y - bf2f(h.y));
        h.z = bfr(v.z); l.z = bfr(v.z - bf2f(h.z));
        h.w = bfr(v.w); l.w = bfr(v.w - bf2f(h.w));
        reinterpret_cast<ushort4*>(hi)[idx] = h;
        reinterpret_cast<ushort4*>(lo)[idx] = l;
    }
}

// ---------------------------------------------------------------------------
// wtrans_split: Wt[n][k] = W[k][n] as hi bf16 (64x64 LDS tile transpose)
// ---------------------------------------------------------------------------
__global__ __launch_bounds__(256) void wtrans_split(const float* __restrict__ W,
                                                    unsigned short* __restrict__ thi) {
    __shared__ float tle[64][65];
    const int n0 = blockIdx.x * 64, k0 = blockIdx.y * 64;
    const int tid = threadIdx.x;
    const int r = tid >> 2, c0 = (tid & 3) * 16;
#pragma unroll
    for (int s = 0; s < 16; s += 4) {
        float4 v = *reinterpret_cast<const float4*>(&W[(size_t)(k0 + r) * DIM + n0 + c0 + s]);
        tle[r][c0 + s + 0] = v.x; tle[r][c0 + s + 1] = v.y;
        tle[r][c0 + s + 2] = v.z; tle[r][c0 + s + 3] = v.w;
    }
    __syncthreads();
#pragma unroll
    for (int s = 0; s < 16; s += 4) {
        ushort4 h;
        h.x = bfr(tle[c0 + s + 0][r]);
        h.y = bfr(tle[c0 + s + 1][r]);
        h.z = bfr(tle[c0 + s + 2][r]);
        h.w = bfr(tle[c0 + s + 3][r]);
        *reinterpret_cast<ushort4*>(&thi[(size_t)(n0 + r) * DIM + k0 + c0 + s]) = h;
    }
}

// ---------------------------------------------------------------------------
// fused_mfma: blockIdx < nbt -> causal 128x128 score tile, split-2 MFMA
//             ( (a_hi+a_lo) . b_hi ), -inf masked, written to sc.
//             blockIdx >= nbt -> y_sem 128x128 tile, hi.hi MFMA, to C.
// 256 thr = 4 waves (2x2); wave owns 64x64 = 4x4 frags of 16x16x32.
// LDS 30KB -> up to 5 blocks/CU.
// ---------------------------------------------------------------------------
__global__ __launch_bounds__(256) void fused_mfma(
        const unsigned short* __restrict__ hhi,
        const unsigned short* __restrict__ hlo,
        const unsigned short* __restrict__ wthi,
        float* __restrict__ sc, float* __restrict__ C,
        int nbt, int b0) {
    __shared__ unsigned short lds[3][128][40];

    const int tid  = threadIdx.x;
    const int lane = tid & 63, wid = tid >> 6;
    const int wr = (wid >> 1) * 64, wc = (wid & 1) * 64;
    const int fr = lane & 15, fc = lane >> 4;
    const int sr = tid >> 1;           // staging row 0..127
    const int sh = (tid & 1) * 16;     // staging half (16 ushorts = 32B)

    f32x4 acc[4][4];
    const f32x4 zz = {0.f, 0.f, 0.f, 0.f};
#pragma unroll
    for (int i = 0; i < 4; ++i)
#pragma unroll
        for (int j = 0; j < 4; ++j) acc[i][j] = zz;

    const int idx = blockIdx.x;

    if (idx < nbt) {
        // ----------------- score tile -----------------
        const int bl = idx / NT2;
        const int t  = idx % NT2;
        const int b  = b0 + bl;
        int qt = (int)((sqrtf(8.f * t + 1.f) - 1.f) * 0.5f);
        while ((qt + 1) * (qt + 2) / 2 <= t) ++qt;
        while (qt * (qt + 1) / 2 > t) --qt;
        const int kt = t - qt * (qt + 1) / 2;

        const size_t base = (size_t)b * SEQT * DIM;
        const unsigned short* Ah = hhi + base + (size_t)(qt * 128) * DIM;
        const unsigned short* Al = hlo + base + (size_t)(qt * 128) * DIM;
        const unsigned short* Bh = hhi + base + (size_t)(kt * 128) * DIM;

        for (int k0 = 0; k0 < DIM; k0 += 32) {
            const size_t ro = (size_t)sr * DIM + k0 + sh;
            int4 a0 = *reinterpret_cast<const int4*>(Ah + ro);
            int4 a1 = *reinterpret_cast<const int4*>(Ah + ro + 8);
            int4 l0 = *reinterpret_cast<const int4*>(Al + ro);
            int4 l1 = *reinterpret_cast<const int4*>(Al + ro + 8);
            int4 b0v = *reinterpret_cast<const int4*>(Bh + ro);
            int4 b1v = *reinterpret_cast<const int4*>(Bh + ro + 8);
            __syncthreads();
            *reinterpret_cast<int4*>(&lds[0][sr][sh])     = a0;
            *reinterpret_cast<int4*>(&lds[0][sr][sh + 8]) = a1;
            *reinterpret_cast<int4*>(&lds[1][sr][sh])     = l0;
            *reinterpret_cast<int4*>(&lds[1][sr][sh + 8]) = l1;
            *reinterpret_cast<int4*>(&lds[2][sr][sh])     = b0v;
            *reinterpret_cast<int4*>(&lds[2][sr][sh + 8]) = b1v;
            __syncthreads();

            short8 ah[4], al4[4], bh4[4];
#pragma unroll
            for (int f = 0; f < 4; ++f) {
                ah[f]  = *reinterpret_cast<const short8*>(&lds[0][wr + f * 16 + fr][fc * 8]);
                al4[f] = *reinterpret_cast<const short8*>(&lds[1][wr + f * 16 + fr][fc * 8]);
                bh4[f] = *reinterpret_cast<const short8*>(&lds[2][wc + f * 16 + fr][fc * 8]);
            }
#pragma unroll
            for (int i = 0; i < 4; ++i)
#pragma unroll
                for (int j = 0; j < 4; ++j) {
                    acc[i][j] = __builtin_amdgcn_mfma_f32_16x16x32_bf16(ah[i],  bh4[j], acc[i][j], 0, 0, 0);
                    acc[i][j] = __builtin_amdgcn_mfma_f32_16x16x32_bf16(al4[i], bh4[j], acc[i][j], 0, 0, 0);
                }
        }

        float* tile = sc + ((size_t)bl * NT2 + t) * 16384;
        const bool diag = (qt == kt);
#pragma unroll
        for (int i = 0; i < 4; ++i)
#pragma unroll
            for (int j = 0; j < 4; ++j)
#pragma unroll
                for (int v = 0; v < 4; ++v) {
                    const int row = wr + i * 16 + fc * 4 + v;
                    const int col = wc + j * 16 + fr;
                    float val = acc[i][j][v] * SCALE;
                    if (diag && col >= row) val = -INFINITY;
                    tile[row * 128 + col] = val;
                }
    } else {
        // ----------------- y_sem tile -----------------
        const int y  = idx - nbt;
        const int m0 = (y >> 3) * 128;      // row tile
        const int n0 = (y & 7) * 128;       // col tile
        const unsigned short* Ah = hhi + (size_t)m0 * DIM;
        const unsigned short* Bh = wthi + (size_t)n0 * DIM;

        for (int k0 = 0; k0 < DIM; k0 += 32) {
            const size_t ro = (size_t)sr * DIM + k0 + sh;
            int4 a0 = *reinterpret_cast<const int4*>(Ah + ro);
            int4 a1 = *reinterpret_cast<const int4*>(Ah + ro + 8);
            int4 b0v = *reinterpret_cast<const int4*>(Bh + ro);
            int4 b1v = *reinterpret_cast<const int4*>(Bh + ro + 8);
            __syncthreads();
            *reinterpret_cast<int4*>(&lds[0][sr][sh])     = a0;
            *reinterpret_cast<int4*>(&lds[0][sr][sh + 8]) = a1;
            *reinterpret_cast<int4*>(&lds[2][sr][sh])     = b0v;
            *reinterpret_cast<int4*>(&lds[2][sr][sh + 8]) = b1v;
            __syncthreads();

            short8 ah[4], bh4[4];
#pragma unroll
            for (int f = 0; f < 4; ++f) {
                ah[f]  = *reinterpret_cast<const short8*>(&lds[0][wr + f * 16 + fr][fc * 8]);
                bh4[f] = *reinterpret_cast<const short8*>(&lds[2][wc + f * 16 + fr][fc * 8]);
            }
#pragma unroll
            for (int i = 0; i < 4; ++i)
#pragma unroll
                for (int j = 0; j < 4; ++j)
                    acc[i][j] = __builtin_amdgcn_mfma_f32_16x16x32_bf16(ah[i], bh4[j], acc[i][j], 0, 0, 0);
        }

#pragma unroll
        for (int i = 0; i < 4; ++i)
#pragma unroll
            for (int j = 0; j < 4; ++j)
#pragma unroll
                for (int v = 0; v < 4; ++v) {
                    const int row = wr + i * 16 + fc * 4 + v;
                    const int col = wc + j * 16 + fr;
                    C[(size_t)(m0 + row) * DIM + n0 + col] = acc[i][j][v] * SCALE;
                }
    }
}

// ---------------------------------------------------------------------------
// Kernel 3: exact top-64 per row. Radix histogram (valid elements only) +
// parallel suffix-sum bin search + tie ranking + fp64 boundary fixup.
// ---------------------------------------------------------------------------
__device__ __forceinline__ unsigned flipf(float v) {
    unsigned bu = __float_as_uint(v);
    return bu ^ ((unsigned)((int)bu >> 31) | 0x80000000u);
}

__global__ __launch_bounds__(256) void row_topk(const float* __restrict__ hs,
                                                const float* __restrict__ sc,
                                                float* __restrict__ lv,
                                                int* __restrict__ li, int b0) {
    const int bl = blockIdx.x >> 11;
    const int i  = blockIdx.x & 2047;
    const int b  = b0 + bl;
    const int tid = threadIdx.x;

    float* outv = lv + (((size_t)b * SEQT + i) << 6);
    int*   outi = li + (((size_t)b * SEQT + i) << 6);
    const size_t batch_off = (size_t)bl * NT2 * 16384;

    if (i <= KTOP) {
        if (tid < KTOP) {
            float v = 0.f;
            int   ix = 0;
            if (tid < i) {
                v  = sc[batch_off + (size_t)i * 128 + tid];
                ix = tid;
            }
            outv[tid] = v;
            outi[tid] = ix;
        }
        return;
    }

    const int qt = i >> 7, r = i & 127;
    const int nscan = (qt + 1) * 128;
    const size_t rowb = batch_off + ((size_t)(qt * (qt + 1) / 2)) * 16384 + (size_t)r * 128;

    float    ev[8];
    unsigned eu[8];
#pragma unroll
    for (int s = 0; s < 8; ++s) {
        const int j = tid + (s << 8);
        ev[s] = (j < nscan) ? sc[rowb + ((size_t)(j >> 7)) * 16384 + (j & 127)] : -INFINITY;
        eu[s] = flipf(ev[s]);
    }

    __shared__ int hist[2048];
    __shared__ int wtot[4];
    __shared__ int sfxs[257];
    __shared__ int hv[8];
    __shared__ int sB, sM;
    __shared__ int ocnt, ccnt;
    if (tid == 0) { ocnt = 0; ccnt = 0; }
    for (int h = tid; h < 2048; h += 256) hist[h] = 0;
    __syncthreads();
#pragma unroll
    for (int s = 0; s < 8; ++s) {
        const int j = tid + (s << 8);
        if (j < nscan && ev[s] != -INFINITY) atomicAdd(&hist[eu[s] >> 21], 1);
    }
    __syncthreads();

    int part = 0;
#pragma unroll
    for (int h = 0; h < 8; ++h) part += hist[tid * 8 + h];
    const int lane = tid & 63, w = tid >> 6;
    int sfx = part;
#pragma unroll
    for (int off = 1; off < 64; off <<= 1) {
        int o = __shfl_down(sfx, off, 64);
        if (lane + off < 64) sfx += o;
    }
    if (lane == 0) wtot[w] = sfx;
    __syncthreads();
#pragma unroll
    for (int w2 = 0; w2 < 4; ++w2)
        if (w2 > w) sfx += wtot[w2];
    sfxs[tid] = sfx;
    if (tid == 255) sfxs[256] = 0;
    const int nflag = __syncthreads_count(sfx >= KTOP);
    const int gs = nflag - 1;
    if (tid < 8) hv[tid] = hist[gs * 8 + tid];
    __syncthreads();
    if (tid == 0) {
        const int hh[8] = {hv[0], hv[1], hv[2], hv[3], hv[4], hv[5], hv[6], hv[7]};
        int acc = sfxs[gs + 1];
        int B = gs * 8;
        for (int h = 7; h >= 0; --h) {
            if (acc + hh[h] >= KTOP) { B = gs * 8 + h; break; }
            acc += hh[h];
        }
        sB = B;
        sM = acc;
    }
    __syncthreads();
    const unsigned B = (unsigned)sB;
    const int m = sM;
    const int tn = KTOP - m;

    __shared__ unsigned cu[512];
    __shared__ float    cva[512];
    __shared__ int      cix[512];
    __shared__ float    lsv[64];

#pragma unroll
    for (int s = 0; s < 8; ++s) {
        const int j = tid + (s << 8);
        if (j < nscan && ev[s] != -INFINITY) {
            const unsigned bin = eu[s] >> 21;
            if (bin > B) {
                int p = atomicAdd(&ocnt, 1);
                outv[p] = ev[s];
                outi[p] = j;
                lsv[p]  = ev[s];
            } else if (bin == B) {
                int p = atomicAdd(&ccnt, 1);
                if (p < 512) { cu[p] = eu[s]; cva[p] = ev[s]; cix[p] = j; }
            }
        }
    }
    __syncthreads();
    const int cb = (ccnt < 512) ? ccnt : 512;

    for (int c = tid; c < cb; c += 256) {
        const unsigned u = cu[c];
        const int ix = cix[c];
        int rk = 0;
        for (int c2 = 0; c2 < cb; ++c2) {
            const unsigned u2 = cu[c2];
            rk += (u2 > u) || (u2 == u && cix[c2] < ix);
        }
        if (rk < tn) { outv[m + rk] = cva[c]; outi[m + rk] = ix; lsv[m + rk] = cva[c]; }
    }

    // ---------------- fp64 boundary fixup ----------------
    __shared__ float  svmin;
    __shared__ int    tcnt;
    __shared__ int    spos[64];
    __shared__ double dval[256];
    __syncthreads();
    if (tid == 0) {
        float mv = lsv[0];
        for (int k = 1; k < KTOP; ++k) mv = fminf(mv, lsv[k]);
        svmin = mv;
        ccnt = 0;
        tcnt = 0;
    }
    __syncthreads();
    const float vmin = svmin;
#pragma unroll
    for (int s = 0; s < 8; ++s) {
        const int j = tid + (s << 8);
        if (j < nscan && fabsf(ev[s] - vmin) <= DELTA) {
            int p = atomicAdd(&ccnt, 1);
            if (p < 256) { cva[p] = ev[s]; cix[p] = j; }
        }
    }
    __syncthreads();
    const int mb = ccnt;
    if (mb < 2 || mb > 256) return;

    if (tid < KTOP && fabsf(lsv[tid] - vmin) <= DELTA) {
        int q = atomicAdd(&tcnt, 1);
        spos[q] = tid;
    }
    __syncthreads();
    const int t = tcnt;

    const int wid = tid >> 6;
    const float* qrow = hs + ((size_t)b * SEQT + i) * DIM;
    for (int c = wid; c < mb; c += 4) {
        const float* krow = hs + ((size_t)b * SEQT + cix[c]) * DIM;
        double acc = 0.0;
        for (int d = lane; d < DIM; d += 64)
            acc += (double)qrow[d] * (double)krow[d];
#pragma unroll
        for (int off = 32; off; off >>= 1) acc += __shfl_xor(acc, off, 64);
        if (lane == 0) dval[c] = acc;
    }
    __syncthreads();

    if (tid < mb) {
        const double dv = dval[tid];
        const int ix = cix[tid];
        int rk = 0;
        for (int c2 = 0; c2 < mb; ++c2)
            rk += (dval[c2] > dv) || (dval[c2] == dv && cix[c2] < ix);
        if (rk < t) {
            const int pp = spos[rk];
            outv[pp] = cva[tid];
            outi[pp] = ix;
        }
    }
}

// ---------------------------------------------------------------------------
// Kernel 4 (levels 1-2): gather y_episodic from bf16-hi rows (L2-resident),
// gate, final output. XCD-batch affinity: batch = (blockIdx%8)>>1.
// ---------------------------------------------------------------------------
__global__ __launch_bounds__(512) void gather_bf16(const unsigned short* __restrict__ hhi,
                                                   const float* __restrict__ lv,
                                                   const int* __restrict__ li,
                                                   float* __restrict__ io) {
    const int tid  = threadIdx.x;
    const int lane = tid & 63;
    const int wid  = tid >> 6;
    const int blk  = blockIdx.x;
    const int xs   = blk & 7;
    const int b    = xs >> 1;
    const int rg   = (blk >> 3) * 2 + (xs & 1);
    const int i    = rg * 8 + wid;

    const size_t row = (size_t)b * SEQT + i;
    const float4* v4 = reinterpret_cast<const float4*>(lv + (row << 6));
    const int4*   i4 = reinterpret_cast<const int4*>(li + (row << 6));
    const unsigned short* hb = hhi + (size_t)b * SEQT * DIM;
    const int d0 = lane * 8;

    float y[16];
#pragma unroll
    for (int t = 0; t < 16; ++t) y[t] = 0.f;

#pragma unroll 2
    for (int kk = 0; kk < 16; ++kk) {
        const float4 vv = v4[kk];
        const int4   ii = i4[kk];
        const float  vs[4] = {vv.x, vv.y, vv.z, vv.w};
        const int    js[4] = {ii.x, ii.y, ii.z, ii.w};
#pragma unroll
        for (int c = 0; c < 4; ++c) {
            const float v = vs[c];
            const unsigned short* hr = hb + (size_t)js[c] * DIM + d0;
            uint4 w0 = *reinterpret_cast<const uint4*>(hr);
            uint4 w1 = *reinterpret_cast<const uint4*>(hr + 512);
            const unsigned wa[8] = {w0.x, w0.y, w0.z, w0.w, w1.x, w1.y, w1.z, w1.w};
#pragma unroll
            for (int e = 0; e < 8; ++e) {
                float flo = __uint_as_float(wa[e] << 16);
                float fhi = __uint_as_float(wa[e] & 0xffff0000u);
                y[2 * e + 0] += v * flo;
                y[2 * e + 1] += v * fhi;
            }
        }
    }

    float* iorow = io + row * DIM;
    float4 s0 = *reinterpret_cast<const float4*>(iorow + d0);
    float4 s1 = *reinterpret_cast<const float4*>(iorow + d0 + 4);
    float4 s2 = *reinterpret_cast<const float4*>(iorow + 512 + d0);
    float4 s3 = *reinterpret_cast<const float4*>(iorow + 512 + d0 + 4);
    const float ss[16] = {s0.x, s0.y, s0.z, s0.w, s1.x, s1.y, s1.z, s1.w,
                          s2.x, s2.y, s2.z, s2.w, s3.x, s3.y, s3.z, s3.w};
    float p = 0.f;
#pragma unroll
    for (int t = 0; t < 16; ++t) p += y[t] * ss[t];
#pragma unroll
    for (int off = 32; off; off >>= 1) p += __shfl_xor(p, off, 64);
    const float g  = 1.f / (1.f + __expf(-p));
    const float og = 1.f - g;
    float o[16];
#pragma unroll
    for (int t = 0; t < 16; ++t) o[t] = g * y[t] + og * ss[t];
    *reinterpret_cast<float4*>(iorow + d0)           = *reinterpret_cast<float4*>(&o[0]);
    *reinterpret_cast<float4*>(iorow + d0 + 4)       = *reinterpret_cast<float4*>(&o[4]);
    *reinterpret_cast<float4*>(iorow + 512 + d0)     = *reinterpret_cast<float4*>(&o[8]);
    *reinterpret_cast<float4*>(iorow + 512 + d0 + 4) = *reinterpret_cast<float4*>(&o[12]);
}

// ---------------------------------------------------------------------------
// Kernel 4 (level-3 fallback): fp32 gather.
// ---------------------------------------------------------------------------
__global__ __launch_bounds__(512) void merge_gather(const float* __restrict__ hs,
                                                    const float* __restrict__ lv,
                                                    const int* __restrict__ li,
                                                    float* __restrict__ io) {
    const int tid  = threadIdx.x;
    const int lane = tid & 63;
    const int wid  = tid >> 6;
    const int b    = blockIdx.x >> 7;
    const int r0   = (blockIdx.x & 127) * 16;
    const float* hb = hs + (size_t)b * SEQT * DIM;
    const int dofs = lane * 4;

    for (int rr = wid; rr < 16; rr += 8) {
        const int i = r0 + rr;
        const size_t row = (size_t)b * SEQT + i;
        const float4* v4 = reinterpret_cast<const float4*>(lv + (row << 6));
        const int4*   i4 = reinterpret_cast<const int4*>(li + (row << 6));

        float4 y0 = {0.f, 0.f, 0.f, 0.f}, y1 = y0, y2 = y0, y3 = y0;
#pragma unroll 4
        for (int kk = 0; kk < 16; ++kk) {
            const float4 vv = v4[kk];
            const int4   ii = i4[kk];
            const float  vs[4] = {vv.x, vv.y, vv.z, vv.w};
            const int    js[4] = {ii.x, ii.y, ii.z, ii.w};
#pragma unroll
            for (int c = 0; c < 4; ++c) {
                const float v = vs[c];
                const float* hr = hb + (size_t)js[c] * DIM + dofs;
                float4 a = *reinterpret_cast<const float4*>(hr);
                float4 cc = *reinterpret_cast<const float4*>(hr + 256);
                float4 d = *reinterpret_cast<const float4*>(hr + 512);
                float4 e = *reinterpret_cast<const float4*>(hr + 768);
                y0.x += v * a.x;  y0.y += v * a.y;  y0.z += v * a.z;  y0.w += v * a.w;
                y1.x += v * cc.x; y1.y += v * cc.y; y1.z += v * cc.z; y1.w += v * cc.w;
                y2.x += v * d.x;  y2.y += v * d.y;  y2.z += v * d.z;  y2.w += v * d.w;
                y3.x += v * e.x;  y3.y += v * e.y;  y3.z += v * e.z;  y3.w += v * e.w;
            }
        }

        float* iorow = io + row * DIM + dofs;
        float4 s0 = *reinterpret_cast<const float4*>(iorow);
        float4 s1 = *reinterpret_cast<const float4*>(iorow + 256);
        float4 s2 = *reinterpret_cast<const float4*>(iorow + 512);
        float4 s3 = *reinterpret_cast<const float4*>(iorow + 768);
        float p = y0.x * s0.x + y0.y * s0.y + y0.z * s0.z + y0.w * s0.w
                + y1.x * s1.x + y1.y * s1.y + y1.z * s1.z + y1.w * s1.w
                + y2.x * s2.x + y2.y * s2.y + y2.z * s2.z + y2.w * s2.w
                + y3.x * s3.x + y3.y * s3.y + y3.z * s3.z + y3.w * s3.w;
#pragma unroll
        for (int off = 32; off; off >>= 1) p += __shfl_xor(p, off, 64);
        const float g  = 1.f / (1.f + __expf(-p));
        const float og = 1.f - g;
        float4 o0, o1, o2, o3;
        o0.x = g * y0.x + og * s0.x; o0.y = g * y0.y + og * s0.y;
        o0.z = g * y0.z + og * s0.z; o0.w = g * y0.w + og * s0.w;
        o1.x = g * y1.x + og * s1.x; o1.y = g * y1.y + og * s1.y;
        o1.z = g * y1.z + og * s1.z; o1.w = g * y1.w + og * s1.w;
        o2.x = g * y2.x + og * s2.x; o2.y = g * y2.y + og * s2.y;
        o2.z = g * y2.z + og * s2.z; o2.w = g * y2.w + og * s2.w;
        o3.x = g * y3.x + og * s3.x; o3.y = g * y3.y + og * s3.y;
        o3.z = g * y3.z + og * s3.z; o3.w = g * y3.w + og * s3.w;
        *reinterpret_cast<float4*>(iorow)       = o0;
        *reinterpret_cast<float4*>(iorow + 256) = o1;
        *reinterpret_cast<float4*>(iorow + 512) = o2;
        *reinterpret_cast<float4*>(iorow + 768) = o3;
    }
}

// ---------------------------------------------------------------------------
extern "C" void kernel_launch(void* const* d_in, const int* in_sizes, int n_in,
                              void* d_out, int out_size, void* d_ws, size_t ws_size,
                              hipStream_t stream) {
    const float* hs = (const float*)d_in[0];
    const float* W  = (const float*)d_in[1];
    float* out = (float*)d_out;

    const size_t Hfull  = (size_t)NB * SEQT * DIM;     // 8388608
    const size_t Hb     = (size_t)SEQT * DIM;          // 2097152
    const size_t Wn     = (size_t)DIM * DIM;           // 1048576
    const size_t Lf     = (size_t)NB * SEQT * KTOP;    // 524288
    const size_t SCfull = (size_t)NB * NT2 * 16384;
    const size_t SCb    = (size_t)NT2 * 16384;

    auto need = [&](size_t H, size_t SC) {
        return (2 * H + 2 * Wn) * sizeof(unsigned short) + Lf * 8 + SC * 4;
    };
    int level = (need(Hfull, SCfull) <= ws_size) ? 1
              : (need(Hfull, SCb) <= ws_size)    ? 2 : 3;

    const size_t H  = (level == 3) ? Hb : Hfull;

    unsigned short* hhi  = (unsigned short*)d_ws;
    unsigned short* hlo  = hhi + H;
    unsigned short* wthi = hlo + H;
    unsigned short* wtlo = wthi + Wn;   // reserved (layout compat)
    float* lv = (float*)(wtlo + Wn);
    int*   li = (int*)(lv + Lf);
    float* sc = (float*)(li + Lf);

    wtrans_split<<<dim3(16, 16), dim3(256), 0, stream>>>(W, wthi);

    if (level == 1) {
        split_bf16<<<dim3(2048), dim3(256), 0, stream>>>(hs, hhi, hlo, (int)(Hfull / 4));
        const int nbt = NB * NT2;                        // 544 score tiles
        const int nys = ((NB * SEQT) / 128) * (DIM / 128); // 512 ysem tiles
        fused_mfma<<<dim3(nbt + nys), dim3(256), 0, stream>>>(hhi, hlo, wthi, sc, out, nbt, 0);
        row_topk<<<dim3(NB * SEQT), dim3(256), 0, stream>>>(hs, sc, lv, li, 0);
        gather_bf16<<<dim3(1024), dim3(512), 0, stream>>>(hhi, lv, li, out);
    } else if (level == 2) {
        split_bf16<<<dim3(2048), dim3(256), 0, stream>>>(hs, hhi, hlo, (int)(Hfull / 4));
        for (int b = 0; b < NB; ++b) {
            fused_mfma<<<dim3(NT2), dim3(256), 0, stream>>>(hhi, hlo, wthi, sc, out, NT2, b);
            row_topk<<<dim3(SEQT), dim3(256), 0, stream>>>(hs, sc, lv, li, b);
        }
        const int nys = ((NB * SEQT) / 128) * (DIM / 128);
        fused_mfma<<<dim3(nys), dim3(256), 0, stream>>>(hhi, hlo, wthi, sc, out, 0, 0);
        gather_bf16<<<dim3(1024), dim3(512), 0, stream>>>(hhi, lv, li, out);
    } else {
        for (int b = 0; b < NB; ++b) {
            split_bf16<<<dim3(512), dim3(256), 0, stream>>>(hs + (size_t)b * Hb, hhi, hlo, (int)(Hb / 4));
            fused_mfma<<<dim3(NT2), dim3(256), 0, stream>>>(hhi, hlo, wthi, sc, out, NT2, 0);
            row_topk<<<dim3(SEQT), dim3(256), 0, stream>>>(hs, sc, lv, li, b);
            fused_mfma<<<dim3((SEQT / 128) * (DIM / 128)), dim3(256), 0, stream>>>(
                hhi, hlo, wthi, sc, out + (size_t)b * Hb, 0, 0);
        }
        merge_gather<<<dim3(NB * 128), dim3(512), 0, stream>>>(hs, lv, li, out);
    }
}

// Round 10
// 285.253 us; speedup vs baseline: 1.0711x; 1.0711x over previous
//
#include <hip/hip_runtime.h>
#include <hip/hip_bf16.h>
#include <math.h>

#define DIM    1024
#define SEQT   2048
#define NB     4
#define SCALE  0.03125f   // 1/32 = DIM^-0.5, exact power of two
#define KTOP   64
#define NT2    136        // 16*17/2 causal 128x128 tiles per batch
#define DELTA  1e-2f      // fp64-recheck window (split-3 err ~2e-6 << this)

typedef __attribute__((ext_vector_type(8))) short short8;   // 8 bf16 = 4 VGPR
typedef __attribute__((ext_vector_type(4))) float f32x4;    // MFMA C/D frag

// ---- bf16 RNE helpers (manual, deterministic) ------------------------------
__device__ __forceinline__ unsigned short bfr(float x) {
    unsigned u = __float_as_uint(x);
    unsigned r = (u + 0x7fffu + ((u >> 16) & 1u)) >> 16;
    return (unsigned short)r;
}
__device__ __forceinline__ float bf2f(unsigned short h) {
    return __uint_as_float(((unsigned)h) << 16);
}

// ---------------------------------------------------------------------------
// split_bf16: x -> hi = bf16(x), lo = bf16(x - hi)   (grid-stride, float4)
// ---------------------------------------------------------------------------
__global__ __launch_bounds__(256) void split_bf16(const float* __restrict__ x,
                                                  unsigned short* __restrict__ hi,
                                                  unsigned short* __restrict__ lo,
                                                  int n4) {
    const int stride = gridDim.x * 256;
    for (int idx = blockIdx.x * 256 + threadIdx.x; idx < n4; idx += stride) {
        float4 v = reinterpret_cast<const float4*>(x)[idx];
        ushort4 h, l;
        h.x = bfr(v.x); l.x = bfr(v.x - bf2f(h.x));
        h.y = bfr(v.y); l.y = bfr(v.y - bf2f(h.y));
        h.z = bfr(v.z); l.z = bfr(v.z - bf2f(h.z));
        h.w = bfr(v.w); l.w = bfr(v.w - bf2f(h.w));
        reinterpret_cast<ushort4*>(hi)[idx] = h;
        reinterpret_cast<ushort4*>(lo)[idx] = l;
    }
}

// ---------------------------------------------------------------------------
// wtrans_split: Wt[n][k] = W[k][n] as hi/lo bf16 (64x64 LDS tile transpose)
// ---------------------------------------------------------------------------
__global__ __launch_bounds__(256) void wtrans_split(const float* __restrict__ W,
                                                    unsigned short* __restrict__ thi,
                                                    unsigned short* __restrict__ tlo) {
    __shared__ float tle[64][65];
    const int n0 = blockIdx.x * 64, k0 = blockIdx.y * 64;
    const int tid = threadIdx.x;
    const int r = tid >> 2, c0 = (tid & 3) * 16;
#pragma unroll
    for (int s = 0; s < 16; s += 4) {
        float4 v = *reinterpret_cast<const float4*>(&W[(size_t)(k0 + r) * DIM + n0 + c0 + s]);
        tle[r][c0 + s + 0] = v.x; tle[r][c0 + s + 1] = v.y;
        tle[r][c0 + s + 2] = v.z; tle[r][c0 + s + 3] = v.w;
    }
    __syncthreads();
#pragma unroll
    for (int s = 0; s < 16; s += 4) {
        float a0 = tle[c0 + s + 0][r];
        float a1 = tle[c0 + s + 1][r];
        float a2 = tle[c0 + s + 2][r];
        float a3 = tle[c0 + s + 3][r];
        ushort4 h, l;
        h.x = bfr(a0); l.x = bfr(a0 - bf2f(h.x));
        h.y = bfr(a1); l.y = bfr(a1 - bf2f(h.y));
        h.z = bfr(a2); l.z = bfr(a2 - bf2f(h.z));
        h.w = bfr(a3); l.w = bfr(a3 - bf2f(h.w));
        *reinterpret_cast<ushort4*>(&thi[(size_t)(n0 + r) * DIM + k0 + c0 + s]) = h;
        *reinterpret_cast<ushort4*>(&tlo[(size_t)(n0 + r) * DIM + k0 + c0 + s]) = l;
    }
}

// ---------------------------------------------------------------------------
// fused_mfma: blockIdx < nbt -> causal 128x128 score tile (split-3 MFMA:
//             ah.bh + ah.bl + al.bh), -inf masked, written to sc.
//             blockIdx >= nbt -> y_sem 128x128 tile (same split-3 vs W^T).
// 256 thr = 4 waves (2x2); wave owns 64x64 = 4x4 frags of 16x16x32.
// LDS 40KB -> 4 blocks/CU; single launch fills the machine.
// ---------------------------------------------------------------------------
__global__ __launch_bounds__(256) void fused_mfma(
        const unsigned short* __restrict__ hhi,
        const unsigned short* __restrict__ hlo,
        const unsigned short* __restrict__ wthi,
        const unsigned short* __restrict__ wtlo,
        float* __restrict__ sc, float* __restrict__ C,
        int nbt, int b0) {
    __shared__ unsigned short lds[4][128][40];   // Ahi, Alo, Bhi, Blo

    const int tid  = threadIdx.x;
    const int lane = tid & 63, wid = tid >> 6;
    const int wr = (wid >> 1) * 64, wc = (wid & 1) * 64;
    const int fr = lane & 15, fc = lane >> 4;
    const int sr = tid >> 1;           // staging row 0..127
    const int sh = (tid & 1) * 16;     // staging half (16 ushorts = 32B)

    const int idx = blockIdx.x;
    const bool is_score = (idx < nbt);

    const unsigned short *Ah, *Al, *Bh, *Bl;
    int bl = 0, t = 0, qt = 0, kt = 0, m0 = 0, n0 = 0;

    if (is_score) {
        bl = idx / NT2;
        t  = idx % NT2;
        const int b = b0 + bl;
        qt = (int)((sqrtf(8.f * t + 1.f) - 1.f) * 0.5f);
        while ((qt + 1) * (qt + 2) / 2 <= t) ++qt;
        while (qt * (qt + 1) / 2 > t) --qt;
        kt = t - qt * (qt + 1) / 2;
        const size_t base = (size_t)b * SEQT * DIM;
        Ah = hhi + base + (size_t)(qt * 128) * DIM;
        Al = hlo + base + (size_t)(qt * 128) * DIM;
        Bh = hhi + base + (size_t)(kt * 128) * DIM;
        Bl = hlo + base + (size_t)(kt * 128) * DIM;
    } else {
        const int y = idx - nbt;
        m0 = (y >> 3) * 128;
        n0 = (y & 7) * 128;
        Ah = hhi + (size_t)m0 * DIM;
        Al = hlo + (size_t)m0 * DIM;
        Bh = wthi + (size_t)n0 * DIM;
        Bl = wtlo + (size_t)n0 * DIM;
    }

    f32x4 acc[4][4];
    const f32x4 zz = {0.f, 0.f, 0.f, 0.f};
#pragma unroll
    for (int i = 0; i < 4; ++i)
#pragma unroll
        for (int j = 0; j < 4; ++j) acc[i][j] = zz;

    for (int k0 = 0; k0 < DIM; k0 += 32) {
        const size_t ro = (size_t)sr * DIM + k0 + sh;
        int4 a0 = *reinterpret_cast<const int4*>(Ah + ro);
        int4 a1 = *reinterpret_cast<const int4*>(Ah + ro + 8);
        int4 l0 = *reinterpret_cast<const int4*>(Al + ro);
        int4 l1 = *reinterpret_cast<const int4*>(Al + ro + 8);
        int4 b0v = *reinterpret_cast<const int4*>(Bh + ro);
        int4 b1v = *reinterpret_cast<const int4*>(Bh + ro + 8);
        int4 c0v = *reinterpret_cast<const int4*>(Bl + ro);
        int4 c1v = *reinterpret_cast<const int4*>(Bl + ro + 8);
        __syncthreads();
        *reinterpret_cast<int4*>(&lds[0][sr][sh])     = a0;
        *reinterpret_cast<int4*>(&lds[0][sr][sh + 8]) = a1;
        *reinterpret_cast<int4*>(&lds[1][sr][sh])     = l0;
        *reinterpret_cast<int4*>(&lds[1][sr][sh + 8]) = l1;
        *reinterpret_cast<int4*>(&lds[2][sr][sh])     = b0v;
        *reinterpret_cast<int4*>(&lds[2][sr][sh + 8]) = b1v;
        *reinterpret_cast<int4*>(&lds[3][sr][sh])     = c0v;
        *reinterpret_cast<int4*>(&lds[3][sr][sh + 8]) = c1v;
        __syncthreads();

        short8 ah[4], al4[4], bh4[4], bl4[4];
#pragma unroll
        for (int f = 0; f < 4; ++f) {
            ah[f]  = *reinterpret_cast<const short8*>(&lds[0][wr + f * 16 + fr][fc * 8]);
            al4[f] = *reinterpret_cast<const short8*>(&lds[1][wr + f * 16 + fr][fc * 8]);
            bh4[f] = *reinterpret_cast<const short8*>(&lds[2][wc + f * 16 + fr][fc * 8]);
            bl4[f] = *reinterpret_cast<const short8*>(&lds[3][wc + f * 16 + fr][fc * 8]);
        }
#pragma unroll
        for (int i = 0; i < 4; ++i)
#pragma unroll
            for (int j = 0; j < 4; ++j) {
                acc[i][j] = __builtin_amdgcn_mfma_f32_16x16x32_bf16(ah[i],  bh4[j], acc[i][j], 0, 0, 0);
                acc[i][j] = __builtin_amdgcn_mfma_f32_16x16x32_bf16(ah[i],  bl4[j], acc[i][j], 0, 0, 0);
                acc[i][j] = __builtin_amdgcn_mfma_f32_16x16x32_bf16(al4[i], bh4[j], acc[i][j], 0, 0, 0);
            }
    }

    if (is_score) {
        float* tile = sc + ((size_t)bl * NT2 + t) * 16384;
        const bool diag = (qt == kt);
#pragma unroll
        for (int i = 0; i < 4; ++i)
#pragma unroll
            for (int j = 0; j < 4; ++j)
#pragma unroll
                for (int v = 0; v < 4; ++v) {
                    const int row = wr + i * 16 + fc * 4 + v;
                    const int col = wc + j * 16 + fr;
                    float val = acc[i][j][v] * SCALE;
                    if (diag && col >= row) val = -INFINITY;
                    tile[row * 128 + col] = val;
                }
    } else {
#pragma unroll
        for (int i = 0; i < 4; ++i)
#pragma unroll
            for (int j = 0; j < 4; ++j)
#pragma unroll
                for (int v = 0; v < 4; ++v) {
                    const int row = wr + i * 16 + fc * 4 + v;
                    const int col = wc + j * 16 + fr;
                    C[(size_t)(m0 + row) * DIM + n0 + col] = acc[i][j][v] * SCALE;
                }
    }
}

// ---------------------------------------------------------------------------
// Kernel 3: exact top-64 per row. Radix histogram (valid elements only) +
// parallel suffix-sum bin search + tie ranking + fp64 boundary fixup.
// ---------------------------------------------------------------------------
__device__ __forceinline__ unsigned flipf(float v) {
    unsigned bu = __float_as_uint(v);
    return bu ^ ((unsigned)((int)bu >> 31) | 0x80000000u);
}

__global__ __launch_bounds__(256) void row_topk(const float* __restrict__ hs,
                                                const float* __restrict__ sc,
                                                float* __restrict__ lv,
                                                int* __restrict__ li, int b0) {
    const int bl = blockIdx.x >> 11;
    const int i  = blockIdx.x & 2047;
    const int b  = b0 + bl;
    const int tid = threadIdx.x;

    float* outv = lv + (((size_t)b * SEQT + i) << 6);
    int*   outi = li + (((size_t)b * SEQT + i) << 6);
    const size_t batch_off = (size_t)bl * NT2 * 16384;

    if (i <= KTOP) {
        if (tid < KTOP) {
            float v = 0.f;
            int   ix = 0;
            if (tid < i) {
                v  = sc[batch_off + (size_t)i * 128 + tid];
                ix = tid;
            }
            outv[tid] = v;
            outi[tid] = ix;
        }
        return;
    }

    const int qt = i >> 7, r = i & 127;
    const int nscan = (qt + 1) * 128;
    const size_t rowb = batch_off + ((size_t)(qt * (qt + 1) / 2)) * 16384 + (size_t)r * 128;

    float    ev[8];
    unsigned eu[8];
#pragma unroll
    for (int s = 0; s < 8; ++s) {
        const int j = tid + (s << 8);
        ev[s] = (j < nscan) ? sc[rowb + ((size_t)(j >> 7)) * 16384 + (j & 127)] : -INFINITY;
        eu[s] = flipf(ev[s]);
    }

    __shared__ int hist[2048];
    __shared__ int wtot[4];
    __shared__ int sfxs[257];
    __shared__ int hv[8];
    __shared__ int sB, sM;
    __shared__ int ocnt, ccnt;
    if (tid == 0) { ocnt = 0; ccnt = 0; }
    for (int h = tid; h < 2048; h += 256) hist[h] = 0;
    __syncthreads();
#pragma unroll
    for (int s = 0; s < 8; ++s) {
        const int j = tid + (s << 8);
        if (j < nscan && ev[s] != -INFINITY) atomicAdd(&hist[eu[s] >> 21], 1);
    }
    __syncthreads();

    int part = 0;
#pragma unroll
    for (int h = 0; h < 8; ++h) part += hist[tid * 8 + h];
    const int lane = tid & 63, w = tid >> 6;
    int sfx = part;
#pragma unroll
    for (int off = 1; off < 64; off <<= 1) {
        int o = __shfl_down(sfx, off, 64);
        if (lane + off < 64) sfx += o;
    }
    if (lane == 0) wtot[w] = sfx;
    __syncthreads();
#pragma unroll
    for (int w2 = 0; w2 < 4; ++w2)
        if (w2 > w) sfx += wtot[w2];
    sfxs[tid] = sfx;
    if (tid == 255) sfxs[256] = 0;
    const int nflag = __syncthreads_count(sfx >= KTOP);
    const int gs = nflag - 1;
    if (tid < 8) hv[tid] = hist[gs * 8 + tid];
    __syncthreads();
    if (tid == 0) {
        const int hh[8] = {hv[0], hv[1], hv[2], hv[3], hv[4], hv[5], hv[6], hv[7]};
        int acc = sfxs[gs + 1];
        int B = gs * 8;
        for (int h = 7; h >= 0; --h) {
            if (acc + hh[h] >= KTOP) { B = gs * 8 + h; break; }
            acc += hh[h];
        }
        sB = B;
        sM = acc;
    }
    __syncthreads();
    const unsigned B = (unsigned)sB;
    const int m = sM;
    const int tn = KTOP - m;

    __shared__ unsigned cu[512];
    __shared__ float    cva[512];
    __shared__ int      cix[512];
    __shared__ float    lsv[64];

#pragma unroll
    for (int s = 0; s < 8; ++s) {
        const int j = tid + (s << 8);
        if (j < nscan && ev[s] != -INFINITY) {
            const unsigned bin = eu[s] >> 21;
            if (bin > B) {
                int p = atomicAdd(&ocnt, 1);
                outv[p] = ev[s];
                outi[p] = j;
                lsv[p]  = ev[s];
            } else if (bin == B) {
                int p = atomicAdd(&ccnt, 1);
                if (p < 512) { cu[p] = eu[s]; cva[p] = ev[s]; cix[p] = j; }
            }
        }
    }
    __syncthreads();
    const int cb = (ccnt < 512) ? ccnt : 512;

    for (int c = tid; c < cb; c += 256) {
        const unsigned u = cu[c];
        const int ix = cix[c];
        int rk = 0;
        for (int c2 = 0; c2 < cb; ++c2) {
            const unsigned u2 = cu[c2];
            rk += (u2 > u) || (u2 == u && cix[c2] < ix);
        }
        if (rk < tn) { outv[m + rk] = cva[c]; outi[m + rk] = ix; lsv[m + rk] = cva[c]; }
    }

    // ---------------- fp64 boundary fixup ----------------
    __shared__ float  svmin;
    __shared__ int    tcnt;
    __shared__ int    spos[64];
    __shared__ double dval[256];
    __syncthreads();
    if (tid == 0) {
        float mv = lsv[0];
        for (int k = 1; k < KTOP; ++k) mv = fminf(mv, lsv[k]);
        svmin = mv;
        ccnt = 0;
        tcnt = 0;
    }
    __syncthreads();
    const float vmin = svmin;
#pragma unroll
    for (int s = 0; s < 8; ++s) {
        const int j = tid + (s << 8);
        if (j < nscan && fabsf(ev[s] - vmin) <= DELTA) {
            int p = atomicAdd(&ccnt, 1);
            if (p < 256) { cva[p] = ev[s]; cix[p] = j; }
        }
    }
    __syncthreads();
    const int mb = ccnt;
    if (mb < 2 || mb > 256) return;

    if (tid < KTOP && fabsf(lsv[tid] - vmin) <= DELTA) {
        int q = atomicAdd(&tcnt, 1);
        spos[q] = tid;
    }
    __syncthreads();
    const int t = tcnt;

    const int wid = tid >> 6;
    const float* qrow = hs + ((size_t)b * SEQT + i) * DIM;
    for (int c = wid; c < mb; c += 4) {
        const float* krow = hs + ((size_t)b * SEQT + cix[c]) * DIM;
        double acc = 0.0;
        for (int d = lane; d < DIM; d += 64)
            acc += (double)qrow[d] * (double)krow[d];
#pragma unroll
        for (int off = 32; off; off >>= 1) acc += __shfl_xor(acc, off, 64);
        if (lane == 0) dval[c] = acc;
    }
    __syncthreads();

    if (tid < mb) {
        const double dv = dval[tid];
        const int ix = cix[tid];
        int rk = 0;
        for (int c2 = 0; c2 < mb; ++c2)
            rk += (dval[c2] > dv) || (dval[c2] == dv && cix[c2] < ix);
        if (rk < t) {
            const int pp = spos[rk];
            outv[pp] = cva[tid];
            outi[pp] = ix;
        }
    }
}

// ---------------------------------------------------------------------------
// Kernel 4 (levels 1-2): gather y_episodic from bf16-hi rows (L2-resident),
// gate, final output. XCD-batch affinity: batch = (blockIdx%8)>>1.
// ---------------------------------------------------------------------------
__global__ __launch_bounds__(512) void gather_bf16(const unsigned short* __restrict__ hhi,
                                                   const float* __restrict__ lv,
                                                   const int* __restrict__ li,
                                                   float* __restrict__ io) {
    const int tid  = threadIdx.x;
    const int lane = tid & 63;
    const int wid  = tid >> 6;
    const int blk  = blockIdx.x;
    const int xs   = blk & 7;
    const int b    = xs >> 1;
    const int rg   = (blk >> 3) * 2 + (xs & 1);
    const int i    = rg * 8 + wid;

    const size_t row = (size_t)b * SEQT + i;
    const float4* v4 = reinterpret_cast<const float4*>(lv + (row << 6));
    const int4*   i4 = reinterpret_cast<const int4*>(li + (row << 6));
    const unsigned short* hb = hhi + (size_t)b * SEQT * DIM;
    const int d0 = lane * 8;

    float y[16];
#pragma unroll
    for (int t = 0; t < 16; ++t) y[t] = 0.f;

#pragma unroll 2
    for (int kk = 0; kk < 16; ++kk) {
        const float4 vv = v4[kk];
        const int4   ii = i4[kk];
        const float  vs[4] = {vv.x, vv.y, vv.z, vv.w};
        const int    js[4] = {ii.x, ii.y, ii.z, ii.w};
#pragma unroll
        for (int c = 0; c < 4; ++c) {
            const float v = vs[c];
            const unsigned short* hr = hb + (size_t)js[c] * DIM + d0;
            uint4 w0 = *reinterpret_cast<const uint4*>(hr);
            uint4 w1 = *reinterpret_cast<const uint4*>(hr + 512);
            const unsigned wa[8] = {w0.x, w0.y, w0.z, w0.w, w1.x, w1.y, w1.z, w1.w};
#pragma unroll
            for (int e = 0; e < 8; ++e) {
                float flo = __uint_as_float(wa[e] << 16);
                float fhi = __uint_as_float(wa[e] & 0xffff0000u);
                y[2 * e + 0] += v * flo;
                y[2 * e + 1] += v * fhi;
            }
        }
    }

    float* iorow = io + row * DIM;
    float4 s0 = *reinterpret_cast<const float4*>(iorow + d0);
    float4 s1 = *reinterpret_cast<const float4*>(iorow + d0 + 4);
    float4 s2 = *reinterpret_cast<const float4*>(iorow + 512 + d0);
    float4 s3 = *reinterpret_cast<const float4*>(iorow + 512 + d0 + 4);
    const float ss[16] = {s0.x, s0.y, s0.z, s0.w, s1.x, s1.y, s1.z, s1.w,
                          s2.x, s2.y, s2.z, s2.w, s3.x, s3.y, s3.z, s3.w};
    float p = 0.f;
#pragma unroll
    for (int t = 0; t < 16; ++t) p += y[t] * ss[t];
#pragma unroll
    for (int off = 32; off; off >>= 1) p += __shfl_xor(p, off, 64);
    const float g  = 1.f / (1.f + __expf(-p));
    const float og = 1.f - g;
    float o[16];
#pragma unroll
    for (int t = 0; t < 16; ++t) o[t] = g * y[t] + og * ss[t];
    *reinterpret_cast<float4*>(iorow + d0)           = *reinterpret_cast<float4*>(&o[0]);
    *reinterpret_cast<float4*>(iorow + d0 + 4)       = *reinterpret_cast<float4*>(&o[4]);
    *reinterpret_cast<float4*>(iorow + 512 + d0)     = *reinterpret_cast<float4*>(&o[8]);
    *reinterpret_cast<float4*>(iorow + 512 + d0 + 4) = *reinterpret_cast<float4*>(&o[12]);
}

// ---------------------------------------------------------------------------
// Kernel 4 (level-3 fallback): fp32 gather.
// ---------------------------------------------------------------------------
__global__ __launch_bounds__(512) void merge_gather(const float* __restrict__ hs,
                                                    const float* __restrict__ lv,
                                                    const int* __restrict__ li,
                                                    float* __restrict__ io) {
    const int tid  = threadIdx.x;
    const int lane = tid & 63;
    const int wid  = tid >> 6;
    const int b    = blockIdx.x >> 7;
    const int r0   = (blockIdx.x & 127) * 16;
    const float* hb = hs + (size_t)b * SEQT * DIM;
    const int dofs = lane * 4;

    for (int rr = wid; rr < 16; rr += 8) {
        const int i = r0 + rr;
        const size_t row = (size_t)b * SEQT + i;
        const float4* v4 = reinterpret_cast<const float4*>(lv + (row << 6));
        const int4*   i4 = reinterpret_cast<const int4*>(li + (row << 6));

        float4 y0 = {0.f, 0.f, 0.f, 0.f}, y1 = y0, y2 = y0, y3 = y0;
#pragma unroll 4
        for (int kk = 0; kk < 16; ++kk) {
            const float4 vv = v4[kk];
            const int4   ii = i4[kk];
            const float  vs[4] = {vv.x, vv.y, vv.z, vv.w};
            const int    js[4] = {ii.x, ii.y, ii.z, ii.w};
#pragma unroll
            for (int c = 0; c < 4; ++c) {
                const float v = vs[c];
                const float* hr = hb + (size_t)js[c] * DIM + dofs;
                float4 a = *reinterpret_cast<const float4*>(hr);
                float4 cc = *reinterpret_cast<const float4*>(hr + 256);
                float4 d = *reinterpret_cast<const float4*>(hr + 512);
                float4 e = *reinterpret_cast<const float4*>(hr + 768);
                y0.x += v * a.x;  y0.y += v * a.y;  y0.z += v * a.z;  y0.w += v * a.w;
                y1.x += v * cc.x; y1.y += v * cc.y; y1.z += v * cc.z; y1.w += v * cc.w;
                y2.x += v * d.x;  y2.y += v * d.y;  y2.z += v * d.z;  y2.w += v * d.w;
                y3.x += v * e.x;  y3.y += v * e.y;  y3.z += v * e.z;  y3.w += v * e.w;
            }
        }

        float* iorow = io + row * DIM + dofs;
        float4 s0 = *reinterpret_cast<const float4*>(iorow);
        float4 s1 = *reinterpret_cast<const float4*>(iorow + 256);
        float4 s2 = *reinterpret_cast<const float4*>(iorow + 512);
        float4 s3 = *reinterpret_cast<const float4*>(iorow + 768);
        float p = y0.x * s0.x + y0.y * s0.y + y0.z * s0.z + y0.w * s0.w
                + y1.x * s1.x + y1.y * s1.y + y1.z * s1.z + y1.w * s1.w
                + y2.x * s2.x + y2.y * s2.y + y2.z * s2.z + y2.w * s2.w
                + y3.x * s3.x + y3.y * s3.y + y3.z * s3.z + y3.w * s3.w;
#pragma unroll
        for (int off = 32; off; off >>= 1) p += __shfl_xor(p, off, 64);
        const float g  = 1.f / (1.f + __expf(-p));
        const float og = 1.f - g;
        float4 o0, o1, o2, o3;
        o0.x = g * y0.x + og * s0.x; o0.y = g * y0.y + og * s0.y;
        o0.z = g * y0.z + og * s0.z; o0.w = g * y0.w + og * s0.w;
        o1.x = g * y1.x + og * s1.x; o1.y = g * y1.y + og * s1.y;
        o1.z = g * y1.z + og * s1.z; o1.w = g * y1.w + og * s1.w;
        o2.x = g * y2.x + og * s2.x; o2.y = g * y2.y + og * s2.y;
        o2.z = g * y2.z + og * s2.z; o2.w = g * y2.w + og * s2.w;
        o3.x = g * y3.x + og * s3.x; o3.y = g * y3.y + og * s3.y;
        o3.z = g * y3.z + og * s3.z; o3.w = g * y3.w + og * s3.w;
        *reinterpret_cast<float4*>(iorow)       = o0;
        *reinterpret_cast<float4*>(iorow + 256) = o1;
        *reinterpret_cast<float4*>(iorow + 512) = o2;
        *reinterpret_cast<float4*>(iorow + 768) = o3;
    }
}

// ---------------------------------------------------------------------------
extern "C" void kernel_launch(void* const* d_in, const int* in_sizes, int n_in,
                              void* d_out, int out_size, void* d_ws, size_t ws_size,
                              hipStream_t stream) {
    const float* hs = (const float*)d_in[0];
    const float* W  = (const float*)d_in[1];
    float* out = (float*)d_out;

    const size_t Hfull  = (size_t)NB * SEQT * DIM;     // 8388608
    const size_t Hb     = (size_t)SEQT * DIM;          // 2097152
    const size_t Wn     = (size_t)DIM * DIM;           // 1048576
    const size_t Lf     = (size_t)NB * SEQT * KTOP;    // 524288
    const size_t SCfull = (size_t)NB * NT2 * 16384;
    const size_t SCb    = (size_t)NT2 * 16384;

    auto need = [&](size_t H, size_t SC) {
        return (2 * H + 2 * Wn) * sizeof(unsigned short) + Lf * 8 + SC * 4;
    };
    int level = (need(Hfull, SCfull) <= ws_size) ? 1
              : (need(Hfull, SCb) <= ws_size)    ? 2 : 3;

    const size_t H  = (level == 3) ? Hb : Hfull;

    unsigned short* hhi  = (unsigned short*)d_ws;
    unsigned short* hlo  = hhi + H;
    unsigned short* wthi = hlo + H;
    unsigned short* wtlo = wthi + Wn;
    float* lv = (float*)(wtlo + Wn);
    int*   li = (int*)(lv + Lf);
    float* sc = (float*)(li + Lf);

    wtrans_split<<<dim3(16, 16), dim3(256), 0, stream>>>(W, wthi, wtlo);

    if (level == 1) {
        split_bf16<<<dim3(2048), dim3(256), 0, stream>>>(hs, hhi, hlo, (int)(Hfull / 4));
        const int nbt = NB * NT2;                          // 544 score tiles
        const int nys = ((NB * SEQT) / 128) * (DIM / 128); // 512 ysem tiles
        fused_mfma<<<dim3(nbt + nys), dim3(256), 0, stream>>>(hhi, hlo, wthi, wtlo, sc, out, nbt, 0);
        row_topk<<<dim3(NB * SEQT), dim3(256), 0, stream>>>(hs, sc, lv, li, 0);
        gather_bf16<<<dim3(1024), dim3(512), 0, stream>>>(hhi, lv, li, out);
    } else if (level == 2) {
        split_bf16<<<dim3(2048), dim3(256), 0, stream>>>(hs, hhi, hlo, (int)(Hfull / 4));
        for (int b = 0; b < NB; ++b) {
            fused_mfma<<<dim3(NT2), dim3(256), 0, stream>>>(hhi, hlo, wthi, wtlo, sc, out, NT2, b);
            row_topk<<<dim3(SEQT), dim3(256), 0, stream>>>(hs, sc, lv, li, b);
        }
        const int nys = ((NB * SEQT) / 128) * (DIM / 128);
        fused_mfma<<<dim3(nys), dim3(256), 0, stream>>>(hhi, hlo, wthi, wtlo, sc, out, 0, 0);
        gather_bf16<<<dim3(1024), dim3(512), 0, stream>>>(hhi, lv, li, out);
    } else {
        for (int b = 0; b < NB; ++b) {
            split_bf16<<<dim3(512), dim3(256), 0, stream>>>(hs + (size_t)b * Hb, hhi, hlo, (int)(Hb / 4));
            fused_mfma<<<dim3(NT2), dim3(256), 0, stream>>>(hhi, hlo, wthi, wtlo, sc, out, NT2, 0);
            row_topk<<<dim3(SEQT), dim3(256), 0, stream>>>(hs, sc, lv, li, b);
            fused_mfma<<<dim3((SEQT / 128) * (DIM / 128)), dim3(256), 0, stream>>>(
                hhi, hlo, wthi, wtlo, sc, out + (size_t)b * Hb, 0, 0);
        }
        merge_gather<<<dim3(NB * 128), dim3(512), 0, stream>>>(hs, lv, li, out);
    }
}

// Round 11
// 278.657 us; speedup vs baseline: 1.0965x; 1.0237x over previous
//
#include <hip/hip_runtime.h>
#include <hip/hip_bf16.h>
#include <math.h>

#define DIM    1024
#define SEQT   2048
#define NB     4
#define SCALE  0.03125f   // 1/32 = DIM^-0.5, exact power of two
#define KTOP   64
#define NT2    136        // 16*17/2 causal 128x128 tiles per batch
#define DELTA  1e-2f      // fp64-recheck window (split-3 err ~2e-6 << this)

typedef __attribute__((ext_vector_type(8))) short short8;   // 8 bf16 = 4 VGPR
typedef __attribute__((ext_vector_type(4))) float f32x4;    // MFMA C/D frag

// ---- bf16 RNE helpers (manual, deterministic) ------------------------------
__device__ __forceinline__ unsigned short bfr(float x) {
    unsigned u = __float_as_uint(x);
    unsigned r = (u + 0x7fffu + ((u >> 16) & 1u)) >> 16;
    return (unsigned short)r;
}
__device__ __forceinline__ float bf2f(unsigned short h) {
    return __uint_as_float(((unsigned)h) << 16);
}

// ---------------------------------------------------------------------------
// split_bf16: x -> hi = bf16(x), lo = bf16(x - hi)   (grid-stride, float4)
// ---------------------------------------------------------------------------
__global__ __launch_bounds__(256) void split_bf16(const float* __restrict__ x,
                                                  unsigned short* __restrict__ hi,
                                                  unsigned short* __restrict__ lo,
                                                  int n4) {
    const int stride = gridDim.x * 256;
    for (int idx = blockIdx.x * 256 + threadIdx.x; idx < n4; idx += stride) {
        float4 v = reinterpret_cast<const float4*>(x)[idx];
        ushort4 h, l;
        h.x = bfr(v.x); l.x = bfr(v.x - bf2f(h.x));
        h.y = bfr(v.y); l.y = bfr(v.y - bf2f(h.y));
        h.z = bfr(v.z); l.z = bfr(v.z - bf2f(h.z));
        h.w = bfr(v.w); l.w = bfr(v.w - bf2f(h.w));
        reinterpret_cast<ushort4*>(hi)[idx] = h;
        reinterpret_cast<ushort4*>(lo)[idx] = l;
    }
}

// ---------------------------------------------------------------------------
// wtrans_split: Wt[n][k] = W[k][n] as hi/lo bf16 (64x64 LDS tile transpose)
// ---------------------------------------------------------------------------
__global__ __launch_bounds__(256) void wtrans_split(const float* __restrict__ W,
                                                    unsigned short* __restrict__ thi,
                                                    unsigned short* __restrict__ tlo) {
    __shared__ float tle[64][65];
    const int n0 = blockIdx.x * 64, k0 = blockIdx.y * 64;
    const int tid = threadIdx.x;
    const int r = tid >> 2, c0 = (tid & 3) * 16;
#pragma unroll
    for (int s = 0; s < 16; s += 4) {
        float4 v = *reinterpret_cast<const float4*>(&W[(size_t)(k0 + r) * DIM + n0 + c0 + s]);
        tle[r][c0 + s + 0] = v.x; tle[r][c0 + s + 1] = v.y;
        tle[r][c0 + s + 2] = v.z; tle[r][c0 + s + 3] = v.w;
    }
    __syncthreads();
#pragma unroll
    for (int s = 0; s < 16; s += 4) {
        float a0 = tle[c0 + s + 0][r];
        float a1 = tle[c0 + s + 1][r];
        float a2 = tle[c0 + s + 2][r];
        float a3 = tle[c0 + s + 3][r];
        ushort4 h, l;
        h.x = bfr(a0); l.x = bfr(a0 - bf2f(h.x));
        h.y = bfr(a1); l.y = bfr(a1 - bf2f(h.y));
        h.z = bfr(a2); l.z = bfr(a2 - bf2f(h.z));
        h.w = bfr(a3); l.w = bfr(a3 - bf2f(h.w));
        *reinterpret_cast<ushort4*>(&thi[(size_t)(n0 + r) * DIM + k0 + c0 + s]) = h;
        *reinterpret_cast<ushort4*>(&tlo[(size_t)(n0 + r) * DIM + k0 + c0 + s]) = l;
    }
}

// ---------------------------------------------------------------------------
// fused_mfma: blockIdx < nbt -> causal 128x128 score tile (split-3 MFMA),
//             blockIdx >= nbt -> y_sem 128x128 tile (split-3 vs W^T).
// Staging write bijection h = (t&1)^((sr>>3)&1) de-aliases the 4-way LDS
// write conflict (rows 8 apart share a bank class; the flipped half offsets
// them by 8 banks -> max 2-way, which is free).
// ---------------------------------------------------------------------------
__global__ __launch_bounds__(256) void fused_mfma(
        const unsigned short* __restrict__ hhi,
        const unsigned short* __restrict__ hlo,
        const unsigned short* __restrict__ wthi,
        const unsigned short* __restrict__ wtlo,
        float* __restrict__ sc, float* __restrict__ C,
        int nbt, int b0) {
    __shared__ unsigned short lds[4][128][40];   // Ahi, Alo, Bhi, Blo

    const int tid  = threadIdx.x;
    const int lane = tid & 63, wid = tid >> 6;
    const int wr = (wid >> 1) * 64, wc = (wid & 1) * 64;
    const int fr = lane & 15, fc = lane >> 4;
    const int sr = tid >> 1;                         // staging row 0..127
    const int hsel = (tid & 1) ^ ((sr >> 3) & 1);    // de-aliased half
    const int sh = hsel * 16;                        // 16 ushorts = 32B

    const int idx = blockIdx.x;
    const bool is_score = (idx < nbt);

    const unsigned short *Ah, *Al, *Bh, *Bl;
    int bl = 0, t = 0, qt = 0, kt = 0, m0 = 0, n0 = 0;

    if (is_score) {
        bl = idx / NT2;
        t  = idx % NT2;
        const int b = b0 + bl;
        qt = (int)((sqrtf(8.f * t + 1.f) - 1.f) * 0.5f);
        while ((qt + 1) * (qt + 2) / 2 <= t) ++qt;
        while (qt * (qt + 1) / 2 > t) --qt;
        kt = t - qt * (qt + 1) / 2;
        const size_t base = (size_t)b * SEQT * DIM;
        Ah = hhi + base + (size_t)(qt * 128) * DIM;
        Al = hlo + base + (size_t)(qt * 128) * DIM;
        Bh = hhi + base + (size_t)(kt * 128) * DIM;
        Bl = hlo + base + (size_t)(kt * 128) * DIM;
    } else {
        const int y = idx - nbt;
        m0 = (y >> 3) * 128;
        n0 = (y & 7) * 128;
        Ah = hhi + (size_t)m0 * DIM;
        Al = hlo + (size_t)m0 * DIM;
        Bh = wthi + (size_t)n0 * DIM;
        Bl = wtlo + (size_t)n0 * DIM;
    }

    f32x4 acc[4][4];
    const f32x4 zz = {0.f, 0.f, 0.f, 0.f};
#pragma unroll
    for (int i = 0; i < 4; ++i)
#pragma unroll
        for (int j = 0; j < 4; ++j) acc[i][j] = zz;

    for (int k0 = 0; k0 < DIM; k0 += 32) {
        const size_t ro = (size_t)sr * DIM + k0 + sh;
        int4 a0 = *reinterpret_cast<const int4*>(Ah + ro);
        int4 a1 = *reinterpret_cast<const int4*>(Ah + ro + 8);
        int4 l0 = *reinterpret_cast<const int4*>(Al + ro);
        int4 l1 = *reinterpret_cast<const int4*>(Al + ro + 8);
        int4 b0v = *reinterpret_cast<const int4*>(Bh + ro);
        int4 b1v = *reinterpret_cast<const int4*>(Bh + ro + 8);
        int4 c0v = *reinterpret_cast<const int4*>(Bl + ro);
        int4 c1v = *reinterpret_cast<const int4*>(Bl + ro + 8);
        __syncthreads();
        *reinterpret_cast<int4*>(&lds[0][sr][sh])     = a0;
        *reinterpret_cast<int4*>(&lds[0][sr][sh + 8]) = a1;
        *reinterpret_cast<int4*>(&lds[1][sr][sh])     = l0;
        *reinterpret_cast<int4*>(&lds[1][sr][sh + 8]) = l1;
        *reinterpret_cast<int4*>(&lds[2][sr][sh])     = b0v;
        *reinterpret_cast<int4*>(&lds[2][sr][sh + 8]) = b1v;
        *reinterpret_cast<int4*>(&lds[3][sr][sh])     = c0v;
        *reinterpret_cast<int4*>(&lds[3][sr][sh + 8]) = c1v;
        __syncthreads();

        short8 ah[4], al4[4], bh4[4], bl4[4];
#pragma unroll
        for (int f = 0; f < 4; ++f) {
            ah[f]  = *reinterpret_cast<const short8*>(&lds[0][wr + f * 16 + fr][fc * 8]);
            al4[f] = *reinterpret_cast<const short8*>(&lds[1][wr + f * 16 + fr][fc * 8]);
            bh4[f] = *reinterpret_cast<const short8*>(&lds[2][wc + f * 16 + fr][fc * 8]);
            bl4[f] = *reinterpret_cast<const short8*>(&lds[3][wc + f * 16 + fr][fc * 8]);
        }
#pragma unroll
        for (int i = 0; i < 4; ++i)
#pragma unroll
            for (int j = 0; j < 4; ++j) {
                acc[i][j] = __builtin_amdgcn_mfma_f32_16x16x32_bf16(ah[i],  bh4[j], acc[i][j], 0, 0, 0);
                acc[i][j] = __builtin_amdgcn_mfma_f32_16x16x32_bf16(ah[i],  bl4[j], acc[i][j], 0, 0, 0);
                acc[i][j] = __builtin_amdgcn_mfma_f32_16x16x32_bf16(al4[i], bh4[j], acc[i][j], 0, 0, 0);
            }
    }

    if (is_score) {
        float* tile = sc + ((size_t)bl * NT2 + t) * 16384;
        const bool diag = (qt == kt);
#pragma unroll
        for (int i = 0; i < 4; ++i)
#pragma unroll
            for (int j = 0; j < 4; ++j)
#pragma unroll
                for (int v = 0; v < 4; ++v) {
                    const int row = wr + i * 16 + fc * 4 + v;
                    const int col = wc + j * 16 + fr;
                    float val = acc[i][j][v] * SCALE;
                    if (diag && col >= row) val = -INFINITY;
                    tile[row * 128 + col] = val;
                }
    } else {
#pragma unroll
        for (int i = 0; i < 4; ++i)
#pragma unroll
            for (int j = 0; j < 4; ++j)
#pragma unroll
                for (int v = 0; v < 4; ++v) {
                    const int row = wr + i * 16 + fc * 4 + v;
                    const int col = wc + j * 16 + fr;
                    C[(size_t)(m0 + row) * DIM + n0 + col] = acc[i][j][v] * SCALE;
                }
    }
}

// ---------------------------------------------------------------------------
// topk_gather: exact top-64 per row (radix histogram + suffix-sum bin search
// + tie ranking + fp64 boundary fixup) with the list kept in LDS, then the
// y_episodic gather from bf16-hi rows, gate, and final output — all in one
// kernel. multi=1: 8192-block launch with XCD-batch affinity mapping.
// ---------------------------------------------------------------------------
__device__ __forceinline__ unsigned flipf(float v) {
    unsigned bu = __float_as_uint(v);
    return bu ^ ((unsigned)((int)bu >> 31) | 0x80000000u);
}

__global__ __launch_bounds__(256) void topk_gather(
        const float* __restrict__ hs, const float* __restrict__ sc,
        const unsigned short* __restrict__ hg, float* __restrict__ io,
        int b0, int multi) {
    int bl, i;
    if (multi) {
        const int xs = blockIdx.x & 7;       // ~XCD slot
        bl = xs >> 1;                        // batch per XCD pair
        i  = ((blockIdx.x >> 3) << 1) | (xs & 1);
    } else {
        bl = 0;
        i  = blockIdx.x;
    }
    const int b = b0 + bl;
    const int tid  = threadIdx.x;
    const int lane = tid & 63, w = tid >> 6;
    const size_t batch_off = (size_t)bl * NT2 * 16384;
    const unsigned short* hb = hg + (multi ? (size_t)bl * SEQT * DIM : (size_t)0);

    __shared__ float topv[64];
    __shared__ int   topi[64];
    __shared__ int hist[2048];
    __shared__ int wtot[4];
    __shared__ int sfxs[257];
    __shared__ int hv[8];
    __shared__ int sB, sM;
    __shared__ int ocnt, ccnt;
    __shared__ unsigned cu[512];
    __shared__ float    cva[512];
    __shared__ int      cix[512];
    __shared__ float  svmin;
    __shared__ int    tcnt;
    __shared__ int    spos[64];
    __shared__ double dval[256];
    __shared__ float redg[4];
    __shared__ float gsh;

    if (i <= KTOP) {
        // n = i <= 64: all causal keys (tile qt=0,kt=0), zero-pad
        if (tid < KTOP) {
            float v = 0.f;
            int   ix = 0;
            if (tid < i) {
                v  = sc[batch_off + (size_t)i * 128 + tid];
                ix = tid;
            }
            topv[tid] = v;
            topi[tid] = ix;
        }
        __syncthreads();
    } else {
        const int qt = i >> 7, r = i & 127;
        const int nscan = (qt + 1) * 128;
        const size_t rowb = batch_off + ((size_t)(qt * (qt + 1) / 2)) * 16384 + (size_t)r * 128;

        float    ev[8];
        unsigned eu[8];
#pragma unroll
        for (int s = 0; s < 8; ++s) {
            const int j = tid + (s << 8);
            ev[s] = (j < nscan) ? sc[rowb + ((size_t)(j >> 7)) * 16384 + (j & 127)] : -INFINITY;
            eu[s] = flipf(ev[s]);
        }

        if (tid == 0) { ocnt = 0; ccnt = 0; }
        for (int h = tid; h < 2048; h += 256) hist[h] = 0;
        __syncthreads();
#pragma unroll
        for (int s = 0; s < 8; ++s) {
            const int j = tid + (s << 8);
            if (j < nscan && ev[s] != -INFINITY) atomicAdd(&hist[eu[s] >> 21], 1);
        }
        __syncthreads();

        int part = 0;
#pragma unroll
        for (int h = 0; h < 8; ++h) part += hist[tid * 8 + h];
        int sfx = part;
#pragma unroll
        for (int off = 1; off < 64; off <<= 1) {
            int o = __shfl_down(sfx, off, 64);
            if (lane + off < 64) sfx += o;
        }
        if (lane == 0) wtot[w] = sfx;
        __syncthreads();
#pragma unroll
        for (int w2 = 0; w2 < 4; ++w2)
            if (w2 > w) sfx += wtot[w2];
        sfxs[tid] = sfx;
        if (tid == 255) sfxs[256] = 0;
        const int nflag = __syncthreads_count(sfx >= KTOP);
        const int gs = nflag - 1;
        if (tid < 8) hv[tid] = hist[gs * 8 + tid];
        __syncthreads();
        if (tid == 0) {
            const int hh[8] = {hv[0], hv[1], hv[2], hv[3], hv[4], hv[5], hv[6], hv[7]};
            int acc = sfxs[gs + 1];
            int B = gs * 8;
            for (int h = 7; h >= 0; --h) {
                if (acc + hh[h] >= KTOP) { B = gs * 8 + h; break; }
                acc += hh[h];
            }
            sB = B;
            sM = acc;
        }
        __syncthreads();
        const unsigned B = (unsigned)sB;
        const int m = sM;
        const int tn = KTOP - m;

        // merged collect: winners straight to topv/topi, boundary bin to rank buf
#pragma unroll
        for (int s = 0; s < 8; ++s) {
            const int j = tid + (s << 8);
            if (j < nscan && ev[s] != -INFINITY) {
                const unsigned bin = eu[s] >> 21;
                if (bin > B) {
                    int p = atomicAdd(&ocnt, 1);
                    topv[p] = ev[s];
                    topi[p] = j;
                } else if (bin == B) {
                    int p = atomicAdd(&ccnt, 1);
                    if (p < 512) { cu[p] = eu[s]; cva[p] = ev[s]; cix[p] = j; }
                }
            }
        }
        __syncthreads();
        const int cb = (ccnt < 512) ? ccnt : 512;

        for (int c = tid; c < cb; c += 256) {
            const unsigned u = cu[c];
            const int ix = cix[c];
            int rk = 0;
            for (int c2 = 0; c2 < cb; ++c2) {
                const unsigned u2 = cu[c2];
                rk += (u2 > u) || (u2 == u && cix[c2] < ix);
            }
            if (rk < tn) { topv[m + rk] = cva[c]; topi[m + rk] = ix; }
        }

        // ---------------- fp64 boundary fixup ----------------
        __syncthreads();
        if (tid == 0) {
            float mv = topv[0];
            for (int k = 1; k < KTOP; ++k) mv = fminf(mv, topv[k]);
            svmin = mv;
            ccnt = 0;
            tcnt = 0;
        }
        __syncthreads();
        const float vmin = svmin;
#pragma unroll
        for (int s = 0; s < 8; ++s) {
            const int j = tid + (s << 8);
            if (j < nscan && fabsf(ev[s] - vmin) <= DELTA) {
                int p = atomicAdd(&ccnt, 1);
                if (p < 256) { cva[p] = ev[s]; cix[p] = j; }
            }
        }
        __syncthreads();
        const int mb = ccnt;
        if (mb >= 2 && mb <= 256) {          // block-uniform guard (no return)
            if (tid < KTOP && fabsf(topv[tid] - vmin) <= DELTA) {
                int q = atomicAdd(&tcnt, 1);
                spos[q] = tid;
            }
            __syncthreads();
            const int t = tcnt;

            const float* qrow = hs + ((size_t)b * SEQT + i) * DIM;
            for (int c = w; c < mb; c += 4) {
                const float* krow = hs + ((size_t)b * SEQT + cix[c]) * DIM;
                double acc = 0.0;
                for (int d = lane; d < DIM; d += 64)
                    acc += (double)qrow[d] * (double)krow[d];
#pragma unroll
                for (int off = 32; off; off >>= 1) acc += __shfl_xor(acc, off, 64);
                if (lane == 0) dval[c] = acc;
            }
            __syncthreads();

            if (tid < mb) {
                const double dv = dval[tid];
                const int ix = cix[tid];
                int rk = 0;
                for (int c2 = 0; c2 < mb; ++c2)
                    rk += (dval[c2] > dv) || (dval[c2] == dv && cix[c2] < ix);
                if (rk < t) {
                    const int pp = spos[rk];
                    topv[pp] = cva[tid];
                    topi[pp] = ix;
                }
            }
        }
        __syncthreads();
    }

    // ---------------- gather + gate + final write ----------------
    const int d0g = tid * 4;                 // 256 thr * 4 = DIM
    float y0 = 0.f, y1 = 0.f, y2 = 0.f, y3 = 0.f;
#pragma unroll 4
    for (int k = 0; k < KTOP; ++k) {
        const float v = topv[k];             // LDS broadcast
        const int   j = topi[k];
        const unsigned* wp = reinterpret_cast<const unsigned*>(hb + (size_t)j * DIM + d0g);
        const unsigned w0 = wp[0], w1 = wp[1];
        y0 += v * __uint_as_float(w0 << 16);
        y1 += v * __uint_as_float(w0 & 0xffff0000u);
        y2 += v * __uint_as_float(w1 << 16);
        y3 += v * __uint_as_float(w1 & 0xffff0000u);
    }

    float* iorow = io + ((size_t)b * SEQT + i) * DIM;
    const float4 ys = *reinterpret_cast<const float4*>(iorow + d0g);
    float p = y0 * ys.x + y1 * ys.y + y2 * ys.z + y3 * ys.w;
#pragma unroll
    for (int off = 32; off; off >>= 1) p += __shfl_xor(p, off, 64);
    if (lane == 0) redg[w] = p;
    __syncthreads();
    if (tid == 0) {
        const float z = redg[0] + redg[1] + redg[2] + redg[3];
        gsh = 1.f / (1.f + __expf(-z));
    }
    __syncthreads();
    const float g = gsh, og = 1.f - g;
    float4 o;
    o.x = g * y0 + og * ys.x;
    o.y = g * y1 + og * ys.y;
    o.z = g * y2 + og * ys.z;
    o.w = g * y3 + og * ys.w;
    *reinterpret_cast<float4*>(iorow + d0g) = o;
}

// ---------------------------------------------------------------------------
extern "C" void kernel_launch(void* const* d_in, const int* in_sizes, int n_in,
                              void* d_out, int out_size, void* d_ws, size_t ws_size,
                              hipStream_t stream) {
    const float* hs = (const float*)d_in[0];
    const float* W  = (const float*)d_in[1];
    float* out = (float*)d_out;

    const size_t Hfull  = (size_t)NB * SEQT * DIM;     // 8388608
    const size_t Hb     = (size_t)SEQT * DIM;          // 2097152
    const size_t Wn     = (size_t)DIM * DIM;           // 1048576
    const size_t SCfull = (size_t)NB * NT2 * 16384;
    const size_t SCb    = (size_t)NT2 * 16384;

    auto need = [&](size_t H, size_t SC) {
        return (2 * H + 2 * Wn) * sizeof(unsigned short) + SC * 4;
    };
    int level = (need(Hfull, SCfull) <= ws_size) ? 1
              : (need(Hfull, SCb) <= ws_size)    ? 2 : 3;

    const size_t H = (level == 3) ? Hb : Hfull;

    unsigned short* hhi  = (unsigned short*)d_ws;
    unsigned short* hlo  = hhi + H;
    unsigned short* wthi = hlo + H;
    unsigned short* wtlo = wthi + Wn;
    float* sc = (float*)(wtlo + Wn);

    wtrans_split<<<dim3(16, 16), dim3(256), 0, stream>>>(W, wthi, wtlo);

    if (level == 1) {
        split_bf16<<<dim3(2048), dim3(256), 0, stream>>>(hs, hhi, hlo, (int)(Hfull / 4));
        const int nbt = NB * NT2;                          // 544 score tiles
        const int nys = ((NB * SEQT) / 128) * (DIM / 128); // 512 ysem tiles
        fused_mfma<<<dim3(nbt + nys), dim3(256), 0, stream>>>(hhi, hlo, wthi, wtlo, sc, out, nbt, 0);
        topk_gather<<<dim3(NB * SEQT), dim3(256), 0, stream>>>(hs, sc, hhi, out, 0, 1);
    } else if (level == 2) {
        split_bf16<<<dim3(2048), dim3(256), 0, stream>>>(hs, hhi, hlo, (int)(Hfull / 4));
        const int nys = ((NB * SEQT) / 128) * (DIM / 128);
        fused_mfma<<<dim3(nys), dim3(256), 0, stream>>>(hhi, hlo, wthi, wtlo, sc, out, 0, 0);
        for (int b = 0; b < NB; ++b) {
            fused_mfma<<<dim3(NT2), dim3(256), 0, stream>>>(hhi, hlo, wthi, wtlo, sc, out, NT2, b);
            topk_gather<<<dim3(SEQT), dim3(256), 0, stream>>>(
                hs, sc, hhi + (size_t)b * Hb, out, b, 0);
        }
    } else {
        for (int b = 0; b < NB; ++b) {
            split_bf16<<<dim3(512), dim3(256), 0, stream>>>(hs + (size_t)b * Hb, hhi, hlo, (int)(Hb / 4));
            fused_mfma<<<dim3(NT2), dim3(256), 0, stream>>>(hhi, hlo, wthi, wtlo, sc, out, NT2, 0);
            fused_mfma<<<dim3((SEQT / 128) * (DIM / 128)), dim3(256), 0, stream>>>(
                hhi, hlo, wthi, wtlo, sc, out + (size_t)b * Hb, 0, 0);
            topk_gather<<<dim3(SEQT), dim3(256), 0, stream>>>(hs, sc, hhi, out, b, 0);
        }
    }
}

// Round 12
// 275.148 us; speedup vs baseline: 1.1105x; 1.0128x over previous
//
#include <hip/hip_runtime.h>
#include <hip/hip_bf16.h>
#include <math.h>

#define DIM    1024
#define SEQT   2048
#define NB     4
#define SCALE  0.03125f   // 1/32 = DIM^-0.5, exact power of two
#define KTOP   64
#define NT2    136        // 16*17/2 causal 128x128 tiles per batch
#define DELTA  1e-2f      // fp64-recheck window (split-3 err ~2e-6 << this)

typedef __attribute__((ext_vector_type(8))) short short8;   // 8 bf16 = 4 VGPR
typedef __attribute__((ext_vector_type(4))) float f32x4;    // MFMA C/D frag

// ---- bf16 RNE helpers (manual, deterministic) ------------------------------
__device__ __forceinline__ unsigned short bfr(float x) {
    unsigned u = __float_as_uint(x);
    unsigned r = (u + 0x7fffu + ((u >> 16) & 1u)) >> 16;
    return (unsigned short)r;
}
__device__ __forceinline__ float bf2f(unsigned short h) {
    return __uint_as_float(((unsigned)h) << 16);
}

// async global->LDS, 16B per lane: lds dest = uniform base + lane*16
__device__ __forceinline__ void gl_lds16(const unsigned short* g, unsigned short* l) {
    __builtin_amdgcn_global_load_lds(
        (const __attribute__((address_space(1))) unsigned int*)g,
        (__attribute__((address_space(3))) unsigned int*)l, 16, 0, 0);
}

// ---------------------------------------------------------------------------
// split_bf16: x -> hi = bf16(x), lo = bf16(x - hi)   (grid-stride, float4)
// ---------------------------------------------------------------------------
__global__ __launch_bounds__(256) void split_bf16(const float* __restrict__ x,
                                                  unsigned short* __restrict__ hi,
                                                  unsigned short* __restrict__ lo,
                                                  int n4) {
    const int stride = gridDim.x * 256;
    for (int idx = blockIdx.x * 256 + threadIdx.x; idx < n4; idx += stride) {
        float4 v = reinterpret_cast<const float4*>(x)[idx];
        ushort4 h, l;
        h.x = bfr(v.x); l.x = bfr(v.x - bf2f(h.x));
        h.y = bfr(v.y); l.y = bfr(v.y - bf2f(h.y));
        h.z = bfr(v.z); l.z = bfr(v.z - bf2f(h.z));
        h.w = bfr(v.w); l.w = bfr(v.w - bf2f(h.w));
        reinterpret_cast<ushort4*>(hi)[idx] = h;
        reinterpret_cast<ushort4*>(lo)[idx] = l;
    }
}

// ---------------------------------------------------------------------------
// wtrans_split: Wt[n][k] = W[k][n] as hi/lo bf16 (64x64 LDS tile transpose)
// ---------------------------------------------------------------------------
__global__ __launch_bounds__(256) void wtrans_split(const float* __restrict__ W,
                                                    unsigned short* __restrict__ thi,
                                                    unsigned short* __restrict__ tlo) {
    __shared__ float tle[64][65];
    const int n0 = blockIdx.x * 64, k0 = blockIdx.y * 64;
    const int tid = threadIdx.x;
    const int r = tid >> 2, c0 = (tid & 3) * 16;
#pragma unroll
    for (int s = 0; s < 16; s += 4) {
        float4 v = *reinterpret_cast<const float4*>(&W[(size_t)(k0 + r) * DIM + n0 + c0 + s]);
        tle[r][c0 + s + 0] = v.x; tle[r][c0 + s + 1] = v.y;
        tle[r][c0 + s + 2] = v.z; tle[r][c0 + s + 3] = v.w;
    }
    __syncthreads();
#pragma unroll
    for (int s = 0; s < 16; s += 4) {
        float a0 = tle[c0 + s + 0][r];
        float a1 = tle[c0 + s + 1][r];
        float a2 = tle[c0 + s + 2][r];
        float a3 = tle[c0 + s + 3][r];
        ushort4 h, l;
        h.x = bfr(a0); l.x = bfr(a0 - bf2f(h.x));
        h.y = bfr(a1); l.y = bfr(a1 - bf2f(h.y));
        h.z = bfr(a2); l.z = bfr(a2 - bf2f(h.z));
        h.w = bfr(a3); l.w = bfr(a3 - bf2f(h.w));
        *reinterpret_cast<ushort4*>(&thi[(size_t)(n0 + r) * DIM + k0 + c0 + s]) = h;
        *reinterpret_cast<ushort4*>(&tlo[(size_t)(n0 + r) * DIM + k0 + c0 + s]) = l;
    }
}

// ---------------------------------------------------------------------------
// fused_mfma: blockIdx < nbt -> causal 128x128 score tile (split-3 MFMA),
//             blockIdx >= nbt -> y_sem 128x128 tile (split-3 vs W^T).
// Staging via global_load_lds width=16 (async DMA, no VGPR transit, no
// manual LDS writes). LDS = 4 linear [128][32] arrays = 32KB.
// ---------------------------------------------------------------------------
__global__ __launch_bounds__(256) void fused_mfma(
        const unsigned short* __restrict__ hhi,
        const unsigned short* __restrict__ hlo,
        const unsigned short* __restrict__ wthi,
        const unsigned short* __restrict__ wtlo,
        float* __restrict__ sc, float* __restrict__ C,
        int nbt, int b0) {
    __shared__ unsigned short lds[4][128][32];   // Ahi, Alo, Bhi, Blo (linear)

    const int tid  = threadIdx.x;
    const int lane = tid & 63, wid = tid >> 6;
    const int wr = (wid >> 1) * 64, wc = (wid & 1) * 64;
    const int fr = lane & 15, fc = lane >> 4;
    const int lr = lane >> 2;            // row within 16-row DMA chunk
    const int lc = (lane & 3) * 8;       // ushort offset within row (16B)

    const int idx = blockIdx.x;
    const bool is_score = (idx < nbt);

    const unsigned short *src[4];
    int bl = 0, t = 0, qt = 0, kt = 0, m0 = 0, n0 = 0;

    if (is_score) {
        bl = idx / NT2;
        t  = idx % NT2;
        const int b = b0 + bl;
        qt = (int)((sqrtf(8.f * t + 1.f) - 1.f) * 0.5f);
        while ((qt + 1) * (qt + 2) / 2 <= t) ++qt;
        while (qt * (qt + 1) / 2 > t) --qt;
        kt = t - qt * (qt + 1) / 2;
        const size_t base = (size_t)b * SEQT * DIM;
        src[0] = hhi + base + (size_t)(qt * 128) * DIM;
        src[1] = hlo + base + (size_t)(qt * 128) * DIM;
        src[2] = hhi + base + (size_t)(kt * 128) * DIM;
        src[3] = hlo + base + (size_t)(kt * 128) * DIM;
    } else {
        const int y = idx - nbt;
        m0 = (y >> 3) * 128;
        n0 = (y & 7) * 128;
        src[0] = hhi + (size_t)m0 * DIM;
        src[1] = hlo + (size_t)m0 * DIM;
        src[2] = wthi + (size_t)n0 * DIM;
        src[3] = wtlo + (size_t)n0 * DIM;
    }

    f32x4 acc[4][4];
    const f32x4 zz = {0.f, 0.f, 0.f, 0.f};
#pragma unroll
    for (int i = 0; i < 4; ++i)
#pragma unroll
        for (int j = 0; j < 4; ++j) acc[i][j] = zz;

    for (int k0 = 0; k0 < DIM; k0 += 32) {
        __syncthreads();   // prior reads complete before DMA overwrites
        // stage 4 arrays x 128 rows x 64B via 8 DMA chunks per wave
#pragma unroll
        for (int c = 0; c < 8; ++c) {
            const int a  = c >> 1;
            const int cc = wid * 2 + (c & 1);            // 16-row chunk 0..7
            gl_lds16(src[a] + (size_t)(cc * 16 + lr) * DIM + k0 + lc,
                     &lds[a][cc * 16][0]);
        }
        __syncthreads();   // compiler drains vmcnt(0) before barrier

        short8 ah[4], al4[4], bh4[4], bl4[4];
#pragma unroll
        for (int f = 0; f < 4; ++f) {
            ah[f]  = *reinterpret_cast<const short8*>(&lds[0][wr + f * 16 + fr][fc * 8]);
            al4[f] = *reinterpret_cast<const short8*>(&lds[1][wr + f * 16 + fr][fc * 8]);
            bh4[f] = *reinterpret_cast<const short8*>(&lds[2][wc + f * 16 + fr][fc * 8]);
            bl4[f] = *reinterpret_cast<const short8*>(&lds[3][wc + f * 16 + fr][fc * 8]);
        }
#pragma unroll
        for (int i = 0; i < 4; ++i)
#pragma unroll
            for (int j = 0; j < 4; ++j) {
                acc[i][j] = __builtin_amdgcn_mfma_f32_16x16x32_bf16(ah[i],  bh4[j], acc[i][j], 0, 0, 0);
                acc[i][j] = __builtin_amdgcn_mfma_f32_16x16x32_bf16(ah[i],  bl4[j], acc[i][j], 0, 0, 0);
                acc[i][j] = __builtin_amdgcn_mfma_f32_16x16x32_bf16(al4[i], bh4[j], acc[i][j], 0, 0, 0);
            }
    }

    if (is_score) {
        float* tile = sc + ((size_t)bl * NT2 + t) * 16384;
        const bool diag = (qt == kt);
#pragma unroll
        for (int i = 0; i < 4; ++i)
#pragma unroll
            for (int j = 0; j < 4; ++j)
#pragma unroll
                for (int v = 0; v < 4; ++v) {
                    const int row = wr + i * 16 + fc * 4 + v;
                    const int col = wc + j * 16 + fr;
                    float val = acc[i][j][v] * SCALE;
                    if (diag && col >= row) val = -INFINITY;
                    tile[row * 128 + col] = val;
                }
    } else {
#pragma unroll
        for (int i = 0; i < 4; ++i)
#pragma unroll
            for (int j = 0; j < 4; ++j)
#pragma unroll
                for (int v = 0; v < 4; ++v) {
                    const int row = wr + i * 16 + fc * 4 + v;
                    const int col = wc + j * 16 + fr;
                    C[(size_t)(m0 + row) * DIM + n0 + col] = acc[i][j][v] * SCALE;
                }
    }
}

// ---------------------------------------------------------------------------
// topk_gather: exact top-64 per row (radix histogram + suffix-sum bin search
// + tie ranking + fp64 boundary fixup) with the list kept in LDS, then the
// y_episodic gather from bf16-hi rows, gate, and final output — one kernel.
// ---------------------------------------------------------------------------
__device__ __forceinline__ unsigned flipf(float v) {
    unsigned bu = __float_as_uint(v);
    return bu ^ ((unsigned)((int)bu >> 31) | 0x80000000u);
}

__global__ __launch_bounds__(256) void topk_gather(
        const float* __restrict__ hs, const float* __restrict__ sc,
        const unsigned short* __restrict__ hg, float* __restrict__ io,
        int b0, int multi) {
    int bl, i;
    if (multi) {
        const int xs = blockIdx.x & 7;       // ~XCD slot
        bl = xs >> 1;                        // batch per XCD pair
        i  = ((blockIdx.x >> 3) << 1) | (xs & 1);
    } else {
        bl = 0;
        i  = blockIdx.x;
    }
    const int b = b0 + bl;
    const int tid  = threadIdx.x;
    const int lane = tid & 63, w = tid >> 6;
    const size_t batch_off = (size_t)bl * NT2 * 16384;
    const unsigned short* hb = hg + (multi ? (size_t)bl * SEQT * DIM : (size_t)0);

    __shared__ float topv[64];
    __shared__ int   topi[64];
    __shared__ int hist[2048];
    __shared__ int wtot[4];
    __shared__ int sfxs[257];
    __shared__ int hv[8];
    __shared__ int sB, sM;
    __shared__ int ocnt, ccnt;
    __shared__ unsigned cu[512];
    __shared__ float    cva[512];
    __shared__ int      cix[512];
    __shared__ float  svmin;
    __shared__ int    tcnt;
    __shared__ int    spos[64];
    __shared__ double dval[256];
    __shared__ float redg[4];
    __shared__ float gsh;

    if (i <= KTOP) {
        if (tid < KTOP) {
            float v = 0.f;
            int   ix = 0;
            if (tid < i) {
                v  = sc[batch_off + (size_t)i * 128 + tid];
                ix = tid;
            }
            topv[tid] = v;
            topi[tid] = ix;
        }
        __syncthreads();
    } else {
        const int qt = i >> 7, r = i & 127;
        const int nscan = (qt + 1) * 128;
        const size_t rowb = batch_off + ((size_t)(qt * (qt + 1) / 2)) * 16384 + (size_t)r * 128;

        float    ev[8];
        unsigned eu[8];
#pragma unroll
        for (int s = 0; s < 8; ++s) {
            const int j = tid + (s << 8);
            ev[s] = (j < nscan) ? sc[rowb + ((size_t)(j >> 7)) * 16384 + (j & 127)] : -INFINITY;
            eu[s] = flipf(ev[s]);
        }

        if (tid == 0) { ocnt = 0; ccnt = 0; }
        for (int h = tid; h < 2048; h += 256) hist[h] = 0;
        __syncthreads();
#pragma unroll
        for (int s = 0; s < 8; ++s) {
            const int j = tid + (s << 8);
            if (j < nscan && ev[s] != -INFINITY) atomicAdd(&hist[eu[s] >> 21], 1);
        }
        __syncthreads();

        int part = 0;
#pragma unroll
        for (int h = 0; h < 8; ++h) part += hist[tid * 8 + h];
        int sfx = part;
#pragma unroll
        for (int off = 1; off < 64; off <<= 1) {
            int o = __shfl_down(sfx, off, 64);
            if (lane + off < 64) sfx += o;
        }
        if (lane == 0) wtot[w] = sfx;
        __syncthreads();
#pragma unroll
        for (int w2 = 0; w2 < 4; ++w2)
            if (w2 > w) sfx += wtot[w2];
        sfxs[tid] = sfx;
        if (tid == 255) sfxs[256] = 0;
        const int nflag = __syncthreads_count(sfx >= KTOP);
        const int gs = nflag - 1;
        if (tid < 8) hv[tid] = hist[gs * 8 + tid];
        __syncthreads();
        if (tid == 0) {
            const int hh[8] = {hv[0], hv[1], hv[2], hv[3], hv[4], hv[5], hv[6], hv[7]};
            int acc = sfxs[gs + 1];
            int B = gs * 8;
            for (int h = 7; h >= 0; --h) {
                if (acc + hh[h] >= KTOP) { B = gs * 8 + h; break; }
                acc += hh[h];
            }
            sB = B;
            sM = acc;
        }
        __syncthreads();
        const unsigned B = (unsigned)sB;
        const int m = sM;
        const int tn = KTOP - m;

#pragma unroll
        for (int s = 0; s < 8; ++s) {
            const int j = tid + (s << 8);
            if (j < nscan && ev[s] != -INFINITY) {
                const unsigned bin = eu[s] >> 21;
                if (bin > B) {
                    int p = atomicAdd(&ocnt, 1);
                    topv[p] = ev[s];
                    topi[p] = j;
                } else if (bin == B) {
                    int p = atomicAdd(&ccnt, 1);
                    if (p < 512) { cu[p] = eu[s]; cva[p] = ev[s]; cix[p] = j; }
                }
            }
        }
        __syncthreads();
        const int cb = (ccnt < 512) ? ccnt : 512;

        for (int c = tid; c < cb; c += 256) {
            const unsigned u = cu[c];
            const int ix = cix[c];
            int rk = 0;
            for (int c2 = 0; c2 < cb; ++c2) {
                const unsigned u2 = cu[c2];
                rk += (u2 > u) || (u2 == u && cix[c2] < ix);
            }
            if (rk < tn) { topv[m + rk] = cva[c]; topi[m + rk] = ix; }
        }

        // ---------------- fp64 boundary fixup ----------------
        __syncthreads();
        if (tid == 0) {
            float mv = topv[0];
            for (int k = 1; k < KTOP; ++k) mv = fminf(mv, topv[k]);
            svmin = mv;
            ccnt = 0;
            tcnt = 0;
        }
        __syncthreads();
        const float vmin = svmin;
#pragma unroll
        for (int s = 0; s < 8; ++s) {
            const int j = tid + (s << 8);
            if (j < nscan && fabsf(ev[s] - vmin) <= DELTA) {
                int p = atomicAdd(&ccnt, 1);
                if (p < 256) { cva[p] = ev[s]; cix[p] = j; }
            }
        }
        __syncthreads();
        const int mb = ccnt;
        if (mb >= 2 && mb <= 256) {          // block-uniform guard
            if (tid < KTOP && fabsf(topv[tid] - vmin) <= DELTA) {
                int q = atomicAdd(&tcnt, 1);
                spos[q] = tid;
            }
            __syncthreads();
            const int t = tcnt;

            const float* qrow = hs + ((size_t)b * SEQT + i) * DIM;
            for (int c = w; c < mb; c += 4) {
                const float* krow = hs + ((size_t)b * SEQT + cix[c]) * DIM;
                double acc = 0.0;
                for (int d = lane; d < DIM; d += 64)
                    acc += (double)qrow[d] * (double)krow[d];
#pragma unroll
                for (int off = 32; off; off >>= 1) acc += __shfl_xor(acc, off, 64);
                if (lane == 0) dval[c] = acc;
            }
            __syncthreads();

            if (tid < mb) {
                const double dv = dval[tid];
                const int ix = cix[tid];
                int rk = 0;
                for (int c2 = 0; c2 < mb; ++c2)
                    rk += (dval[c2] > dv) || (dval[c2] == dv && cix[c2] < ix);
                if (rk < t) {
                    const int pp = spos[rk];
                    topv[pp] = cva[tid];
                    topi[pp] = ix;
                }
            }
        }
        __syncthreads();
    }

    // ---------------- gather + gate + final write ----------------
    const int d0g = tid * 4;                 // 256 thr * 4 = DIM
    float y0 = 0.f, y1 = 0.f, y2 = 0.f, y3 = 0.f;
#pragma unroll 4
    for (int k = 0; k < KTOP; ++k) {
        const float v = topv[k];             // LDS broadcast
        const int   j = topi[k];
        const unsigned* wp = reinterpret_cast<const unsigned*>(hb + (size_t)j * DIM + d0g);
        const unsigned w0 = wp[0], w1 = wp[1];
        y0 += v * __uint_as_float(w0 << 16);
        y1 += v * __uint_as_float(w0 & 0xffff0000u);
        y2 += v * __uint_as_float(w1 << 16);
        y3 += v * __uint_as_float(w1 & 0xffff0000u);
    }

    float* iorow = io + ((size_t)b * SEQT + i) * DIM;
    const float4 ys = *reinterpret_cast<const float4*>(iorow + d0g);
    float p = y0 * ys.x + y1 * ys.y + y2 * ys.z + y3 * ys.w;
#pragma unroll
    for (int off = 32; off; off >>= 1) p += __shfl_xor(p, off, 64);
    if (lane == 0) redg[w] = p;
    __syncthreads();
    if (tid == 0) {
        const float z = redg[0] + redg[1] + redg[2] + redg[3];
        gsh = 1.f / (1.f + __expf(-z));
    }
    __syncthreads();
    const float g = gsh, og = 1.f - g;
    float4 o;
    o.x = g * y0 + og * ys.x;
    o.y = g * y1 + og * ys.y;
    o.z = g * y2 + og * ys.z;
    o.w = g * y3 + og * ys.w;
    *reinterpret_cast<float4*>(iorow + d0g) = o;
}

// ---------------------------------------------------------------------------
extern "C" void kernel_launch(void* const* d_in, const int* in_sizes, int n_in,
                              void* d_out, int out_size, void* d_ws, size_t ws_size,
                              hipStream_t stream) {
    const float* hs = (const float*)d_in[0];
    const float* W  = (const float*)d_in[1];
    float* out = (float*)d_out;

    const size_t Hfull  = (size_t)NB * SEQT * DIM;     // 8388608
    const size_t Hb     = (size_t)SEQT * DIM;          // 2097152
    const size_t Wn     = (size_t)DIM * DIM;           // 1048576
    const size_t SCfull = (size_t)NB * NT2 * 16384;
    const size_t SCb    = (size_t)NT2 * 16384;

    auto need = [&](size_t H, size_t SC) {
        return (2 * H + 2 * Wn) * sizeof(unsigned short) + SC * 4;
    };
    int level = (need(Hfull, SCfull) <= ws_size) ? 1
              : (need(Hfull, SCb) <= ws_size)    ? 2 : 3;

    const size_t H = (level == 3) ? Hb : Hfull;

    unsigned short* hhi  = (unsigned short*)d_ws;
    unsigned short* hlo  = hhi + H;
    unsigned short* wthi = hlo + H;
    unsigned short* wtlo = wthi + Wn;
    float* sc = (float*)(wtlo + Wn);

    wtrans_split<<<dim3(16, 16), dim3(256), 0, stream>>>(W, wthi, wtlo);

    if (level == 1) {
        split_bf16<<<dim3(2048), dim3(256), 0, stream>>>(hs, hhi, hlo, (int)(Hfull / 4));
        const int nbt = NB * NT2;                          // 544 score tiles
        const int nys = ((NB * SEQT) / 128) * (DIM / 128); // 512 ysem tiles
        fused_mfma<<<dim3(nbt + nys), dim3(256), 0, stream>>>(hhi, hlo, wthi, wtlo, sc, out, nbt, 0);
        topk_gather<<<dim3(NB * SEQT), dim3(256), 0, stream>>>(hs, sc, hhi, out, 0, 1);
    } else if (level == 2) {
        split_bf16<<<dim3(2048), dim3(256), 0, stream>>>(hs, hhi, hlo, (int)(Hfull / 4));
        const int nys = ((NB * SEQT) / 128) * (DIM / 128);
        fused_mfma<<<dim3(nys), dim3(256), 0, stream>>>(hhi, hlo, wthi, wtlo, sc, out, 0, 0);
        for (int b = 0; b < NB; ++b) {
            fused_mfma<<<dim3(NT2), dim3(256), 0, stream>>>(hhi, hlo, wthi, wtlo, sc, out, NT2, b);
            topk_gather<<<dim3(SEQT), dim3(256), 0, stream>>>(
                hs, sc, hhi + (size_t)b * Hb, out, b, 0);
        }
    } else {
        for (int b = 0; b < NB; ++b) {
            split_bf16<<<dim3(512), dim3(256), 0, stream>>>(hs + (size_t)b * Hb, hhi, hlo, (int)(Hb / 4));
            fused_mfma<<<dim3(NT2), dim3(256), 0, stream>>>(hhi, hlo, wthi, wtlo, sc, out, NT2, 0);
            fused_mfma<<<dim3((SEQT / 128) * (DIM / 128)), dim3(256), 0, stream>>>(
                hhi, hlo, wthi, wtlo, sc, out + (size_t)b * Hb, 0, 0);
            topk_gather<<<dim3(SEQT), dim3(256), 0, stream>>>(hs, sc, hhi, out, b, 0);
        }
    }
}

// Round 13
// 264.493 us; speedup vs baseline: 1.1552x; 1.0403x over previous
//
#include <hip/hip_runtime.h>
#include <hip/hip_bf16.h>
#include <math.h>

#define DIM    1024
#define SEQT   2048
#define NB     4
#define SCALE  0.03125f   // 1/32 = DIM^-0.5, exact power of two
#define KTOP   64
#define NT2    136        // 16*17/2 causal 128x128 tiles per batch
#define DELTA  1e-2f      // fp64-recheck window (split-3 err ~2e-6 << this)

typedef __attribute__((ext_vector_type(8))) short short8;   // 8 bf16 = 4 VGPR
typedef __attribute__((ext_vector_type(4))) float f32x4;    // MFMA C/D frag

// ---- bf16 RNE helpers (manual, deterministic) ------------------------------
__device__ __forceinline__ unsigned short bfr(float x) {
    unsigned u = __float_as_uint(x);
    unsigned r = (u + 0x7fffu + ((u >> 16) & 1u)) >> 16;
    return (unsigned short)r;
}
__device__ __forceinline__ float bf2f(unsigned short h) {
    return __uint_as_float(((unsigned)h) << 16);
}

// async global->LDS, 16B per lane: lds dest = uniform base + lane*16
__device__ __forceinline__ void gl_lds16(const unsigned short* g, unsigned short* l) {
    __builtin_amdgcn_global_load_lds(
        (const __attribute__((address_space(1))) unsigned int*)g,
        (__attribute__((address_space(3))) unsigned int*)l, 16, 0, 0);
}

// ---------------------------------------------------------------------------
// split_bf16: x -> hi = bf16(x), lo = bf16(x - hi)   (grid-stride, float4)
// ---------------------------------------------------------------------------
__global__ __launch_bounds__(256) void split_bf16(const float* __restrict__ x,
                                                  unsigned short* __restrict__ hi,
                                                  unsigned short* __restrict__ lo,
                                                  int n4) {
    const int stride = gridDim.x * 256;
    for (int idx = blockIdx.x * 256 + threadIdx.x; idx < n4; idx += stride) {
        float4 v = reinterpret_cast<const float4*>(x)[idx];
        ushort4 h, l;
        h.x = bfr(v.x); l.x = bfr(v.x - bf2f(h.x));
        h.y = bfr(v.y); l.y = bfr(v.y - bf2f(h.y));
        h.z = bfr(v.z); l.z = bfr(v.z - bf2f(h.z));
        h.w = bfr(v.w); l.w = bfr(v.w - bf2f(h.w));
        reinterpret_cast<ushort4*>(hi)[idx] = h;
        reinterpret_cast<ushort4*>(lo)[idx] = l;
    }
}

// ---------------------------------------------------------------------------
// wtrans_split: Wt[n][k] = W[k][n] as hi/lo bf16 (64x64 LDS tile transpose)
// ---------------------------------------------------------------------------
__global__ __launch_bounds__(256) void wtrans_split(const float* __restrict__ W,
                                                    unsigned short* __restrict__ thi,
                                                    unsigned short* __restrict__ tlo) {
    __shared__ float tle[64][65];
    const int n0 = blockIdx.x * 64, k0 = blockIdx.y * 64;
    const int tid = threadIdx.x;
    const int r = tid >> 2, c0 = (tid & 3) * 16;
#pragma unroll
    for (int s = 0; s < 16; s += 4) {
        float4 v = *reinterpret_cast<const float4*>(&W[(size_t)(k0 + r) * DIM + n0 + c0 + s]);
        tle[r][c0 + s + 0] = v.x; tle[r][c0 + s + 1] = v.y;
        tle[r][c0 + s + 2] = v.z; tle[r][c0 + s + 3] = v.w;
    }
    __syncthreads();
#pragma unroll
    for (int s = 0; s < 16; s += 4) {
        float a0 = tle[c0 + s + 0][r];
        float a1 = tle[c0 + s + 1][r];
        float a2 = tle[c0 + s + 2][r];
        float a3 = tle[c0 + s + 3][r];
        ushort4 h, l;
        h.x = bfr(a0); l.x = bfr(a0 - bf2f(h.x));
        h.y = bfr(a1); l.y = bfr(a1 - bf2f(h.y));
        h.z = bfr(a2); l.z = bfr(a2 - bf2f(h.z));
        h.w = bfr(a3); l.w = bfr(a3 - bf2f(h.w));
        *reinterpret_cast<ushort4*>(&thi[(size_t)(n0 + r) * DIM + k0 + c0 + s]) = h;
        *reinterpret_cast<ushort4*>(&tlo[(size_t)(n0 + r) * DIM + k0 + c0 + s]) = l;
    }
}

// ---------------------------------------------------------------------------
// fused_mfma: blockIdx < nbt -> causal 128x128 score tile (split-3 MFMA),
//             blockIdx >= nbt -> y_sem 128x128 tile (split-3 vs W^T).
// 2-phase pipeline: double-buffered LDS; next tile's global_load_lds issued
// right after the barrier, so its latency hides under this tile's MFMAs.
// One barrier per K-step (the barrier's implicit vmcnt(0) drain lands AFTER
// the MFMA block). XCD-bijective blockIdx swizzle for L2 panel locality.
// ---------------------------------------------------------------------------
__global__ __launch_bounds__(256) void fused_mfma(
        const unsigned short* __restrict__ hhi,
        const unsigned short* __restrict__ hlo,
        const unsigned short* __restrict__ wthi,
        const unsigned short* __restrict__ wtlo,
        float* __restrict__ sc, float* __restrict__ C,
        int nbt, int b0) {
    __shared__ unsigned short lds[2][4][128][32];   // dbuf x {Ahi,Alo,Bhi,Blo} = 64KB

    const int tid  = threadIdx.x;
    const int lane = tid & 63, wid = tid >> 6;
    const int wr = (wid >> 1) * 64, wc = (wid & 1) * 64;
    const int fr = lane & 15, fc = lane >> 4;
    const int lr = lane >> 2;            // row within 16-row DMA chunk
    const int lc = (lane & 3) * 8;       // ushort offset within row (16B)

    // XCD-bijective swizzle: each XCD gets a contiguous logical-tile range
    const int nwg = gridDim.x;           // all launches are multiples of 8
    const int idx = (blockIdx.x & 7) * (nwg >> 3) + (blockIdx.x >> 3);
    const bool is_score = (idx < nbt);

    const unsigned short *src[4];
    int bl = 0, t = 0, qt = 0, kt = 0, m0 = 0, n0 = 0;

    if (is_score) {
        bl = idx / NT2;
        t  = idx % NT2;
        const int b = b0 + bl;
        qt = (int)((sqrtf(8.f * t + 1.f) - 1.f) * 0.5f);
        while ((qt + 1) * (qt + 2) / 2 <= t) ++qt;
        while (qt * (qt + 1) / 2 > t) --qt;
        kt = t - qt * (qt + 1) / 2;
        const size_t base = (size_t)b * SEQT * DIM;
        src[0] = hhi + base + (size_t)(qt * 128) * DIM;
        src[1] = hlo + base + (size_t)(qt * 128) * DIM;
        src[2] = hhi + base + (size_t)(kt * 128) * DIM;
        src[3] = hlo + base + (size_t)(kt * 128) * DIM;
    } else {
        const int y = idx - nbt;
        m0 = (y >> 3) * 128;
        n0 = (y & 7) * 128;
        src[0] = hhi + (size_t)m0 * DIM;
        src[1] = hlo + (size_t)m0 * DIM;
        src[2] = wthi + (size_t)n0 * DIM;
        src[3] = wtlo + (size_t)n0 * DIM;
    }

    f32x4 acc[4][4];
    const f32x4 zz = {0.f, 0.f, 0.f, 0.f};
#pragma unroll
    for (int i = 0; i < 4; ++i)
#pragma unroll
        for (int j = 0; j < 4; ++j) acc[i][j] = zz;

    // stage one K-tile (4 arrays x 128 rows x 64B) via 8 DMA chunks per wave
    auto STAGE = [&](int buf, int k0) {
#pragma unroll
        for (int c = 0; c < 8; ++c) {
            const int a  = c >> 1;
            const int cc = wid * 2 + (c & 1);            // 16-row chunk 0..7
            gl_lds16(src[a] + (size_t)(cc * 16 + lr) * DIM + k0 + lc,
                     &lds[buf][a][cc * 16][0]);
        }
    };

    STAGE(0, 0);                          // prologue prefetch
    for (int ks = 0; ks < 32; ++ks) {
        // barrier: (a) drains vmcnt -> stage-ks data arrived (hidden under
        // the PREVIOUS iteration's MFMAs), (b) confirms all waves finished
        // reading the buffer that the next STAGE will overwrite.
        __syncthreads();
        if (ks < 31) STAGE((ks + 1) & 1, (ks + 1) * 32);
        const int cur = ks & 1;

        short8 ah[4], al4[4], bh4[4], bl4[4];
#pragma unroll
        for (int f = 0; f < 4; ++f) {
            ah[f]  = *reinterpret_cast<const short8*>(&lds[cur][0][wr + f * 16 + fr][fc * 8]);
            al4[f] = *reinterpret_cast<const short8*>(&lds[cur][1][wr + f * 16 + fr][fc * 8]);
            bh4[f] = *reinterpret_cast<const short8*>(&lds[cur][2][wc + f * 16 + fr][fc * 8]);
            bl4[f] = *reinterpret_cast<const short8*>(&lds[cur][3][wc + f * 16 + fr][fc * 8]);
        }
#pragma unroll
        for (int i = 0; i < 4; ++i)
#pragma unroll
            for (int j = 0; j < 4; ++j) {
                acc[i][j] = __builtin_amdgcn_mfma_f32_16x16x32_bf16(ah[i],  bh4[j], acc[i][j], 0, 0, 0);
                acc[i][j] = __builtin_amdgcn_mfma_f32_16x16x32_bf16(ah[i],  bl4[j], acc[i][j], 0, 0, 0);
                acc[i][j] = __builtin_amdgcn_mfma_f32_16x16x32_bf16(al4[i], bh4[j], acc[i][j], 0, 0, 0);
            }
    }

    if (is_score) {
        float* tile = sc + ((size_t)bl * NT2 + t) * 16384;
        const bool diag = (qt == kt);
#pragma unroll
        for (int i = 0; i < 4; ++i)
#pragma unroll
            for (int j = 0; j < 4; ++j)
#pragma unroll
                for (int v = 0; v < 4; ++v) {
                    const int row = wr + i * 16 + fc * 4 + v;
                    const int col = wc + j * 16 + fr;
                    float val = acc[i][j][v] * SCALE;
                    if (diag && col >= row) val = -INFINITY;
                    tile[row * 128 + col] = val;
                }
    } else {
#pragma unroll
        for (int i = 0; i < 4; ++i)
#pragma unroll
            for (int j = 0; j < 4; ++j)
#pragma unroll
                for (int v = 0; v < 4; ++v) {
                    const int row = wr + i * 16 + fc * 4 + v;
                    const int col = wc + j * 16 + fr;
                    C[(size_t)(m0 + row) * DIM + n0 + col] = acc[i][j][v] * SCALE;
                }
    }
}

// ---------------------------------------------------------------------------
// topk_gather: exact top-64 per row (radix histogram + suffix-sum bin search
// + tie ranking + fp64 boundary fixup) with the list kept in LDS, then the
// y_episodic gather from bf16-hi rows, gate, and final output — one kernel.
// ---------------------------------------------------------------------------
__device__ __forceinline__ unsigned flipf(float v) {
    unsigned bu = __float_as_uint(v);
    return bu ^ ((unsigned)((int)bu >> 31) | 0x80000000u);
}

__global__ __launch_bounds__(256) void topk_gather(
        const float* __restrict__ hs, const float* __restrict__ sc,
        const unsigned short* __restrict__ hg, float* __restrict__ io,
        int b0, int multi) {
    int bl, i;
    if (multi) {
        const int xs = blockIdx.x & 7;       // ~XCD slot
        bl = xs >> 1;                        // batch per XCD pair
        i  = ((blockIdx.x >> 3) << 1) | (xs & 1);
    } else {
        bl = 0;
        i  = blockIdx.x;
    }
    const int b = b0 + bl;
    const int tid  = threadIdx.x;
    const int lane = tid & 63, w = tid >> 6;
    const size_t batch_off = (size_t)bl * NT2 * 16384;
    const unsigned short* hb = hg + (multi ? (size_t)bl * SEQT * DIM : (size_t)0);

    __shared__ float topv[64];
    __shared__ int   topi[64];
    __shared__ int hist[2048];
    __shared__ int wtot[4];
    __shared__ int sfxs[257];
    __shared__ int hv[8];
    __shared__ int sB, sM;
    __shared__ int ocnt, ccnt;
    __shared__ unsigned cu[512];
    __shared__ float    cva[512];
    __shared__ int      cix[512];
    __shared__ float  svmin;
    __shared__ int    tcnt;
    __shared__ int    spos[64];
    __shared__ double dval[256];
    __shared__ float redg[4];
    __shared__ float gsh;

    if (i <= KTOP) {
        if (tid < KTOP) {
            float v = 0.f;
            int   ix = 0;
            if (tid < i) {
                v  = sc[batch_off + (size_t)i * 128 + tid];
                ix = tid;
            }
            topv[tid] = v;
            topi[tid] = ix;
        }
        __syncthreads();
    } else {
        const int qt = i >> 7, r = i & 127;
        const int nscan = (qt + 1) * 128;
        const size_t rowb = batch_off + ((size_t)(qt * (qt + 1) / 2)) * 16384 + (size_t)r * 128;

        float    ev[8];
        unsigned eu[8];
#pragma unroll
        for (int s = 0; s < 8; ++s) {
            const int j = tid + (s << 8);
            ev[s] = (j < nscan) ? sc[rowb + ((size_t)(j >> 7)) * 16384 + (j & 127)] : -INFINITY;
            eu[s] = flipf(ev[s]);
        }

        if (tid == 0) { ocnt = 0; ccnt = 0; }
        for (int h = tid; h < 2048; h += 256) hist[h] = 0;
        __syncthreads();
#pragma unroll
        for (int s = 0; s < 8; ++s) {
            const int j = tid + (s << 8);
            if (j < nscan && ev[s] != -INFINITY) atomicAdd(&hist[eu[s] >> 21], 1);
        }
        __syncthreads();

        int part = 0;
#pragma unroll
        for (int h = 0; h < 8; ++h) part += hist[tid * 8 + h];
        int sfx = part;
#pragma unroll
        for (int off = 1; off < 64; off <<= 1) {
            int o = __shfl_down(sfx, off, 64);
            if (lane + off < 64) sfx += o;
        }
        if (lane == 0) wtot[w] = sfx;
        __syncthreads();
#pragma unroll
        for (int w2 = 0; w2 < 4; ++w2)
            if (w2 > w) sfx += wtot[w2];
        sfxs[tid] = sfx;
        if (tid == 255) sfxs[256] = 0;
        const int nflag = __syncthreads_count(sfx >= KTOP);
        const int gs = nflag - 1;
        if (tid < 8) hv[tid] = hist[gs * 8 + tid];
        __syncthreads();
        if (tid == 0) {
            const int hh[8] = {hv[0], hv[1], hv[2], hv[3], hv[4], hv[5], hv[6], hv[7]};
            int acc = sfxs[gs + 1];
            int B = gs * 8;
            for (int h = 7; h >= 0; --h) {
                if (acc + hh[h] >= KTOP) { B = gs * 8 + h; break; }
                acc += hh[h];
            }
            sB = B;
            sM = acc;
        }
        __syncthreads();
        const unsigned B = (unsigned)sB;
        const int m = sM;
        const int tn = KTOP - m;

#pragma unroll
        for (int s = 0; s < 8; ++s) {
            const int j = tid + (s << 8);
            if (j < nscan && ev[s] != -INFINITY) {
                const unsigned bin = eu[s] >> 21;
                if (bin > B) {
                    int p = atomicAdd(&ocnt, 1);
                    topv[p] = ev[s];
                    topi[p] = j;
                } else if (bin == B) {
                    int p = atomicAdd(&ccnt, 1);
                    if (p < 512) { cu[p] = eu[s]; cva[p] = ev[s]; cix[p] = j; }
                }
            }
        }
        __syncthreads();
        const int cb = (ccnt < 512) ? ccnt : 512;

        for (int c = tid; c < cb; c += 256) {
            const unsigned u = cu[c];
            const int ix = cix[c];
            int rk = 0;
            for (int c2 = 0; c2 < cb; ++c2) {
                const unsigned u2 = cu[c2];
                rk += (u2 > u) || (u2 == u && cix[c2] < ix);
            }
            if (rk < tn) { topv[m + rk] = cva[c]; topi[m + rk] = ix; }
        }

        // ---------------- fp64 boundary fixup ----------------
        __syncthreads();
        if (tid == 0) {
            float mv = topv[0];
            for (int k = 1; k < KTOP; ++k) mv = fminf(mv, topv[k]);
            svmin = mv;
            ccnt = 0;
            tcnt = 0;
        }
        __syncthreads();
        const float vmin = svmin;
#pragma unroll
        for (int s = 0; s < 8; ++s) {
            const int j = tid + (s << 8);
            if (j < nscan && fabsf(ev[s] - vmin) <= DELTA) {
                int p = atomicAdd(&ccnt, 1);
                if (p < 256) { cva[p] = ev[s]; cix[p] = j; }
            }
        }
        __syncthreads();
        const int mb = ccnt;
        if (mb >= 2 && mb <= 256) {          // block-uniform guard
            if (tid < KTOP && fabsf(topv[tid] - vmin) <= DELTA) {
                int q = atomicAdd(&tcnt, 1);
                spos[q] = tid;
            }
            __syncthreads();
            const int t = tcnt;

            const float* qrow = hs + ((size_t)b * SEQT + i) * DIM;
            for (int c = w; c < mb; c += 4) {
                const float* krow = hs + ((size_t)b * SEQT + cix[c]) * DIM;
                double acc = 0.0;
                for (int d = lane; d < DIM; d += 64)
                    acc += (double)qrow[d] * (double)krow[d];
#pragma unroll
                for (int off = 32; off; off >>= 1) acc += __shfl_xor(acc, off, 64);
                if (lane == 0) dval[c] = acc;
            }
            __syncthreads();

            if (tid < mb) {
                const double dv = dval[tid];
                const int ix = cix[tid];
                int rk = 0;
                for (int c2 = 0; c2 < mb; ++c2)
                    rk += (dval[c2] > dv) || (dval[c2] == dv && cix[c2] < ix);
                if (rk < t) {
                    const int pp = spos[rk];
                    topv[pp] = cva[tid];
                    topi[pp] = ix;
                }
            }
        }
        __syncthreads();
    }

    // ---------------- gather + gate + final write ----------------
    const int d0g = tid * 4;                 // 256 thr * 4 = DIM
    float y0 = 0.f, y1 = 0.f, y2 = 0.f, y3 = 0.f;
#pragma unroll 4
    for (int k = 0; k < KTOP; ++k) {
        const float v = topv[k];             // LDS broadcast
        const int   j = topi[k];
        const unsigned* wp = reinterpret_cast<const unsigned*>(hb + (size_t)j * DIM + d0g);
        const unsigned w0 = wp[0], w1 = wp[1];
        y0 += v * __uint_as_float(w0 << 16);
        y1 += v * __uint_as_float(w0 & 0xffff0000u);
        y2 += v * __uint_as_float(w1 << 16);
        y3 += v * __uint_as_float(w1 & 0xffff0000u);
    }

    float* iorow = io + ((size_t)b * SEQT + i) * DIM;
    const float4 ys = *reinterpret_cast<const float4*>(iorow + d0g);
    float p = y0 * ys.x + y1 * ys.y + y2 * ys.z + y3 * ys.w;
#pragma unroll
    for (int off = 32; off; off >>= 1) p += __shfl_xor(p, off, 64);
    if (lane == 0) redg[w] = p;
    __syncthreads();
    if (tid == 0) {
        const float z = redg[0] + redg[1] + redg[2] + redg[3];
        gsh = 1.f / (1.f + __expf(-z));
    }
    __syncthreads();
    const float g = gsh, og = 1.f - g;
    float4 o;
    o.x = g * y0 + og * ys.x;
    o.y = g * y1 + og * ys.y;
    o.z = g * y2 + og * ys.z;
    o.w = g * y3 + og * ys.w;
    *reinterpret_cast<float4*>(iorow + d0g) = o;
}

// ---------------------------------------------------------------------------
extern "C" void kernel_launch(void* const* d_in, const int* in_sizes, int n_in,
                              void* d_out, int out_size, void* d_ws, size_t ws_size,
                              hipStream_t stream) {
    const float* hs = (const float*)d_in[0];
    const float* W  = (const float*)d_in[1];
    float* out = (float*)d_out;

    const size_t Hfull  = (size_t)NB * SEQT * DIM;     // 8388608
    const size_t Hb     = (size_t)SEQT * DIM;          // 2097152
    const size_t Wn     = (size_t)DIM * DIM;           // 1048576
    const size_t SCfull = (size_t)NB * NT2 * 16384;
    const size_t SCb    = (size_t)NT2 * 16384;

    auto need = [&](size_t H, size_t SC) {
        return (2 * H + 2 * Wn) * sizeof(unsigned short) + SC * 4;
    };
    int level = (need(Hfull, SCfull) <= ws_size) ? 1
              : (need(Hfull, SCb) <= ws_size)    ? 2 : 3;

    const size_t H = (level == 3) ? Hb : Hfull;

    unsigned short* hhi  = (unsigned short*)d_ws;
    unsigned short* hlo  = hhi + H;
    unsigned short* wthi = hlo + H;
    unsigned short* wtlo = wthi + Wn;
    float* sc = (float*)(wtlo + Wn);

    wtrans_split<<<dim3(16, 16), dim3(256), 0, stream>>>(W, wthi, wtlo);

    if (level == 1) {
        split_bf16<<<dim3(2048), dim3(256), 0, stream>>>(hs, hhi, hlo, (int)(Hfull / 4));
        const int nbt = NB * NT2;                          // 544 score tiles
        const int nys = ((NB * SEQT) / 128) * (DIM / 128); // 512 ysem tiles
        fused_mfma<<<dim3(nbt + nys), dim3(256), 0, stream>>>(hhi, hlo, wthi, wtlo, sc, out, nbt, 0);
        topk_gather<<<dim3(NB * SEQT), dim3(256), 0, stream>>>(hs, sc, hhi, out, 0, 1);
    } else if (level == 2) {
        split_bf16<<<dim3(2048), dim3(256), 0, stream>>>(hs, hhi, hlo, (int)(Hfull / 4));
        const int nys = ((NB * SEQT) / 128) * (DIM / 128);
        fused_mfma<<<dim3(nys), dim3(256), 0, stream>>>(hhi, hlo, wthi, wtlo, sc, out, 0, 0);
        for (int b = 0; b < NB; ++b) {
            fused_mfma<<<dim3(NT2), dim3(256), 0, stream>>>(hhi, hlo, wthi, wtlo, sc, out, NT2, b);
            topk_gather<<<dim3(SEQT), dim3(256), 0, stream>>>(
                hs, sc, hhi + (size_t)b * Hb, out, b, 0);
        }
    } else {
        for (int b = 0; b < NB; ++b) {
            split_bf16<<<dim3(512), dim3(256), 0, stream>>>(hs + (size_t)b * Hb, hhi, hlo, (int)(Hb / 4));
            fused_mfma<<<dim3(NT2), dim3(256), 0, stream>>>(hhi, hlo, wthi, wtlo, sc, out, NT2, 0);
            fused_mfma<<<dim3((SEQT / 128) * (DIM / 128)), dim3(256), 0, stream>>>(
                hhi, hlo, wthi, wtlo, sc, out + (size_t)b * Hb, 0, 0);
            topk_gather<<<dim3(SEQT), dim3(256), 0, stream>>>(hs, sc, hhi, out, b, 0);
        }
    }
}

// Round 14
// 262.287 us; speedup vs baseline: 1.1649x; 1.0084x over previous
//
#include <hip/hip_runtime.h>
#include <hip/hip_bf16.h>
#include <math.h>

#define DIM    1024
#define SEQT   2048
#define NB     4
#define SCALE  0.03125f   // 1/32 = DIM^-0.5, exact power of two
#define KTOP   64
#define NT2    136        // 16*17/2 causal 128x128 tiles per batch
#define DELTA  1e-2f      // fp64-recheck window (split-3 err ~2e-6 << this)

typedef __attribute__((ext_vector_type(8))) short short8;   // 8 bf16 = 4 VGPR
typedef __attribute__((ext_vector_type(4))) float f32x4;    // MFMA C/D frag

// ---- bf16 RNE helpers (manual, deterministic) ------------------------------
__device__ __forceinline__ unsigned short bfr(float x) {
    unsigned u = __float_as_uint(x);
    unsigned r = (u + 0x7fffu + ((u >> 16) & 1u)) >> 16;
    return (unsigned short)r;
}
__device__ __forceinline__ float bf2f(unsigned short h) {
    return __uint_as_float(((unsigned)h) << 16);
}

// async global->LDS, 16B per lane: lds dest = uniform base + lane*16
__device__ __forceinline__ void gl_lds16(const unsigned short* g, unsigned short* l) {
    __builtin_amdgcn_global_load_lds(
        (const __attribute__((address_space(1))) unsigned int*)g,
        (__attribute__((address_space(3))) unsigned int*)l, 16, 0, 0);
}

// ---------------------------------------------------------------------------
// split_bf16: x -> hi = bf16(x), lo = bf16(x - hi)   (grid-stride, float4)
// ---------------------------------------------------------------------------
__global__ __launch_bounds__(256) void split_bf16(const float* __restrict__ x,
                                                  unsigned short* __restrict__ hi,
                                                  unsigned short* __restrict__ lo,
                                                  int n4) {
    const int stride = gridDim.x * 256;
    for (int idx = blockIdx.x * 256 + threadIdx.x; idx < n4; idx += stride) {
        float4 v = reinterpret_cast<const float4*>(x)[idx];
        ushort4 h, l;
        h.x = bfr(v.x); l.x = bfr(v.x - bf2f(h.x));
        h.y = bfr(v.y); l.y = bfr(v.y - bf2f(h.y));
        h.z = bfr(v.z); l.z = bfr(v.z - bf2f(h.z));
        h.w = bfr(v.w); l.w = bfr(v.w - bf2f(h.w));
        reinterpret_cast<ushort4*>(hi)[idx] = h;
        reinterpret_cast<ushort4*>(lo)[idx] = l;
    }
}

// ---------------------------------------------------------------------------
// wtrans_split: Wt[n][k] = W[k][n] as hi/lo bf16 (64x64 LDS tile transpose)
// ---------------------------------------------------------------------------
__global__ __launch_bounds__(256) void wtrans_split(const float* __restrict__ W,
                                                    unsigned short* __restrict__ thi,
                                                    unsigned short* __restrict__ tlo) {
    __shared__ float tle[64][65];
    const int n0 = blockIdx.x * 64, k0 = blockIdx.y * 64;
    const int tid = threadIdx.x;
    const int r = tid >> 2, c0 = (tid & 3) * 16;
#pragma unroll
    for (int s = 0; s < 16; s += 4) {
        float4 v = *reinterpret_cast<const float4*>(&W[(size_t)(k0 + r) * DIM + n0 + c0 + s]);
        tle[r][c0 + s + 0] = v.x; tle[r][c0 + s + 1] = v.y;
        tle[r][c0 + s + 2] = v.z; tle[r][c0 + s + 3] = v.w;
    }
    __syncthreads();
#pragma unroll
    for (int s = 0; s < 16; s += 4) {
        float a0 = tle[c0 + s + 0][r];
        float a1 = tle[c0 + s + 1][r];
        float a2 = tle[c0 + s + 2][r];
        float a3 = tle[c0 + s + 3][r];
        ushort4 h, l;
        h.x = bfr(a0); l.x = bfr(a0 - bf2f(h.x));
        h.y = bfr(a1); l.y = bfr(a1 - bf2f(h.y));
        h.z = bfr(a2); l.z = bfr(a2 - bf2f(h.z));
        h.w = bfr(a3); l.w = bfr(a3 - bf2f(h.w));
        *reinterpret_cast<ushort4*>(&thi[(size_t)(n0 + r) * DIM + k0 + c0 + s]) = h;
        *reinterpret_cast<ushort4*>(&tlo[(size_t)(n0 + r) * DIM + k0 + c0 + s]) = l;
    }
}

// ---------------------------------------------------------------------------
// fused_mfma: blockIdx < nbt -> causal 128x128 score tile (split-3 MFMA),
//             blockIdx >= nbt -> y_sem 128x128 tile (split-3 vs W^T).
// 2-phase pipeline (double-buffered LDS, DMA prefetch hidden under MFMAs).
// Bank-conflict fix (rule #21): LDS dest stays LINEAR (DMA requirement);
// the 16B slot of each row is permuted via sp = s ^ ((row>>1)&3) by
// pre-swizzling the GLOBAL source address; reads apply the same XOR.
// Quad pattern (4*row + sp) mod 8 covers all 8 bank-quads twice per 16
// rows -> 2-way aliasing (free) instead of 8-way.
// ---------------------------------------------------------------------------
__global__ __launch_bounds__(256) void fused_mfma(
        const unsigned short* __restrict__ hhi,
        const unsigned short* __restrict__ hlo,
        const unsigned short* __restrict__ wthi,
        const unsigned short* __restrict__ wtlo,
        float* __restrict__ sc, float* __restrict__ C,
        int nbt, int b0) {
    __shared__ unsigned short lds[2][4][128][32];   // dbuf x {Ahi,Alo,Bhi,Blo} = 64KB

    const int tid  = threadIdx.x;
    const int lane = tid & 63, wid = tid >> 6;
    const int wr = (wid >> 1) * 64, wc = (wid & 1) * 64;
    const int fr = lane & 15, fc = lane >> 4;
    const int lr  = lane >> 2;                       // row within 16-row DMA chunk
    // source col pre-swizzle: slot s_p = lane&3 receives logical slot
    // (lane&3) ^ ((row>>1)&3) ; (row>>1)&3 == (lane>>3)&3 within a chunk
    const int lcs = ((lane & 3) ^ ((lane >> 3) & 3)) * 8;
    // read-side swizzled col (ushorts): logical slot fc at row ..+fr
    const int rcs = (fc ^ ((fr >> 1) & 3)) * 8;

    // XCD-bijective swizzle: each XCD gets a contiguous logical-tile range
    const int nwg = gridDim.x;           // all launches are multiples of 8
    const int idx = (blockIdx.x & 7) * (nwg >> 3) + (blockIdx.x >> 3);
    const bool is_score = (idx < nbt);

    const unsigned short *src[4];
    int bl = 0, t = 0, qt = 0, kt = 0, m0 = 0, n0 = 0;

    if (is_score) {
        bl = idx / NT2;
        t  = idx % NT2;
        const int b = b0 + bl;
        qt = (int)((sqrtf(8.f * t + 1.f) - 1.f) * 0.5f);
        while ((qt + 1) * (qt + 2) / 2 <= t) ++qt;
        while (qt * (qt + 1) / 2 > t) --qt;
        kt = t - qt * (qt + 1) / 2;
        const size_t base = (size_t)b * SEQT * DIM;
        src[0] = hhi + base + (size_t)(qt * 128) * DIM;
        src[1] = hlo + base + (size_t)(qt * 128) * DIM;
        src[2] = hhi + base + (size_t)(kt * 128) * DIM;
        src[3] = hlo + base + (size_t)(kt * 128) * DIM;
    } else {
        const int y = idx - nbt;
        m0 = (y >> 3) * 128;
        n0 = (y & 7) * 128;
        src[0] = hhi + (size_t)m0 * DIM;
        src[1] = hlo + (size_t)m0 * DIM;
        src[2] = wthi + (size_t)n0 * DIM;
        src[3] = wtlo + (size_t)n0 * DIM;
    }

    f32x4 acc[4][4];
    const f32x4 zz = {0.f, 0.f, 0.f, 0.f};
#pragma unroll
    for (int i = 0; i < 4; ++i)
#pragma unroll
        for (int j = 0; j < 4; ++j) acc[i][j] = zz;

    // stage one K-tile (4 arrays x 128 rows x 64B) via 8 DMA chunks per wave
    auto STAGE = [&](int buf, int k0) {
#pragma unroll
        for (int c = 0; c < 8; ++c) {
            const int a  = c >> 1;
            const int cc = wid * 2 + (c & 1);            // 16-row chunk 0..7
            gl_lds16(src[a] + (size_t)(cc * 16 + lr) * DIM + k0 + lcs,
                     &lds[buf][a][cc * 16][0]);
        }
    };

    STAGE(0, 0);                          // prologue prefetch
    for (int ks = 0; ks < 32; ++ks) {
        // barrier: (a) drains vmcnt -> stage-ks data arrived (hidden under
        // the PREVIOUS iteration's MFMAs), (b) confirms all waves finished
        // reading the buffer that the next STAGE will overwrite.
        __syncthreads();
        if (ks < 31) STAGE((ks + 1) & 1, (ks + 1) * 32);
        const int cur = ks & 1;

        short8 ah[4], al4[4], bh4[4], bl4[4];
#pragma unroll
        for (int f = 0; f < 4; ++f) {
            ah[f]  = *reinterpret_cast<const short8*>(&lds[cur][0][wr + f * 16 + fr][rcs]);
            al4[f] = *reinterpret_cast<const short8*>(&lds[cur][1][wr + f * 16 + fr][rcs]);
            bh4[f] = *reinterpret_cast<const short8*>(&lds[cur][2][wc + f * 16 + fr][rcs]);
            bl4[f] = *reinterpret_cast<const short8*>(&lds[cur][3][wc + f * 16 + fr][rcs]);
        }
#pragma unroll
        for (int i = 0; i < 4; ++i)
#pragma unroll
            for (int j = 0; j < 4; ++j) {
                acc[i][j] = __builtin_amdgcn_mfma_f32_16x16x32_bf16(ah[i],  bh4[j], acc[i][j], 0, 0, 0);
                acc[i][j] = __builtin_amdgcn_mfma_f32_16x16x32_bf16(ah[i],  bl4[j], acc[i][j], 0, 0, 0);
                acc[i][j] = __builtin_amdgcn_mfma_f32_16x16x32_bf16(al4[i], bh4[j], acc[i][j], 0, 0, 0);
            }
    }

    if (is_score) {
        float* tile = sc + ((size_t)bl * NT2 + t) * 16384;
        const bool diag = (qt == kt);
#pragma unroll
        for (int i = 0; i < 4; ++i)
#pragma unroll
            for (int j = 0; j < 4; ++j)
#pragma unroll
                for (int v = 0; v < 4; ++v) {
                    const int row = wr + i * 16 + fc * 4 + v;
                    const int col = wc + j * 16 + fr;
                    float val = acc[i][j][v] * SCALE;
                    if (diag && col >= row) val = -INFINITY;
                    tile[row * 128 + col] = val;
                }
    } else {
#pragma unroll
        for (int i = 0; i < 4; ++i)
#pragma unroll
            for (int j = 0; j < 4; ++j)
#pragma unroll
                for (int v = 0; v < 4; ++v) {
                    const int row = wr + i * 16 + fc * 4 + v;
                    const int col = wc + j * 16 + fr;
                    C[(size_t)(m0 + row) * DIM + n0 + col] = acc[i][j][v] * SCALE;
                }
    }
}

// ---------------------------------------------------------------------------
// topk_gather: exact top-64 per row (radix histogram + suffix-sum bin search
// + tie ranking + fp64 boundary fixup) with the list kept in LDS, then the
// y_episodic gather from bf16-hi rows, gate, and final output — one kernel.
// ---------------------------------------------------------------------------
__device__ __forceinline__ unsigned flipf(float v) {
    unsigned bu = __float_as_uint(v);
    return bu ^ ((unsigned)((int)bu >> 31) | 0x80000000u);
}

__global__ __launch_bounds__(256) void topk_gather(
        const float* __restrict__ hs, const float* __restrict__ sc,
        const unsigned short* __restrict__ hg, float* __restrict__ io,
        int b0, int multi) {
    int bl, i;
    if (multi) {
        const int xs = blockIdx.x & 7;       // ~XCD slot
        bl = xs >> 1;                        // batch per XCD pair
        i  = ((blockIdx.x >> 3) << 1) | (xs & 1);
    } else {
        bl = 0;
        i  = blockIdx.x;
    }
    const int b = b0 + bl;
    const int tid  = threadIdx.x;
    const int lane = tid & 63, w = tid >> 6;
    const size_t batch_off = (size_t)bl * NT2 * 16384;
    const unsigned short* hb = hg + (multi ? (size_t)bl * SEQT * DIM : (size_t)0);

    // early ys load: independent of the top-k phases; hides HBM latency
    const int d0g = tid * 4;                 // 256 thr * 4 = DIM
    float* iorow = io + ((size_t)b * SEQT + i) * DIM;
    const float4 ys = *reinterpret_cast<const float4*>(iorow + d0g);

    __shared__ float topv[64];
    __shared__ int   topi[64];
    __shared__ int hist[2048];
    __shared__ int wtot[4];
    __shared__ int sfxs[257];
    __shared__ int hv[8];
    __shared__ int sB, sM;
    __shared__ int ocnt, ccnt;
    __shared__ unsigned cu[512];
    __shared__ float    cva[512];
    __shared__ int      cix[512];
    __shared__ float  svmin;
    __shared__ int    tcnt;
    __shared__ int    spos[64];
    __shared__ double dval[256];
    __shared__ float redg[4];
    __shared__ float gsh;

    if (i <= KTOP) {
        if (tid < KTOP) {
            float v = 0.f;
            int   ix = 0;
            if (tid < i) {
                v  = sc[batch_off + (size_t)i * 128 + tid];
                ix = tid;
            }
            topv[tid] = v;
            topi[tid] = ix;
        }
        __syncthreads();
    } else {
        const int qt = i >> 7, r = i & 127;
        const int nscan = (qt + 1) * 128;
        const size_t rowb = batch_off + ((size_t)(qt * (qt + 1) / 2)) * 16384 + (size_t)r * 128;

        float    ev[8];
        unsigned eu[8];
#pragma unroll
        for (int s = 0; s < 8; ++s) {
            const int j = tid + (s << 8);
            ev[s] = (j < nscan) ? sc[rowb + ((size_t)(j >> 7)) * 16384 + (j & 127)] : -INFINITY;
            eu[s] = flipf(ev[s]);
        }

        if (tid == 0) { ocnt = 0; ccnt = 0; }
        for (int h = tid; h < 2048; h += 256) hist[h] = 0;
        __syncthreads();
#pragma unroll
        for (int s = 0; s < 8; ++s) {
            const int j = tid + (s << 8);
            if (j < nscan && ev[s] != -INFINITY) atomicAdd(&hist[eu[s] >> 21], 1);
        }
        __syncthreads();

        int part = 0;
#pragma unroll
        for (int h = 0; h < 8; ++h) part += hist[tid * 8 + h];
        int sfx = part;
#pragma unroll
        for (int off = 1; off < 64; off <<= 1) {
            int o = __shfl_down(sfx, off, 64);
            if (lane + off < 64) sfx += o;
        }
        if (lane == 0) wtot[w] = sfx;
        __syncthreads();
#pragma unroll
        for (int w2 = 0; w2 < 4; ++w2)
            if (w2 > w) sfx += wtot[w2];
        sfxs[tid] = sfx;
        if (tid == 255) sfxs[256] = 0;
        const int nflag = __syncthreads_count(sfx >= KTOP);
        const int gs = nflag - 1;
        if (tid < 8) hv[tid] = hist[gs * 8 + tid];
        __syncthreads();
        if (tid == 0) {
            const int hh[8] = {hv[0], hv[1], hv[2], hv[3], hv[4], hv[5], hv[6], hv[7]};
            int acc = sfxs[gs + 1];
            int B = gs * 8;
            for (int h = 7; h >= 0; --h) {
                if (acc + hh[h] >= KTOP) { B = gs * 8 + h; break; }
                acc += hh[h];
            }
            sB = B;
            sM = acc;
        }
        __syncthreads();
        const unsigned B = (unsigned)sB;
        const int m = sM;
        const int tn = KTOP - m;

#pragma unroll
        for (int s = 0; s < 8; ++s) {
            const int j = tid + (s << 8);
            if (j < nscan && ev[s] != -INFINITY) {
                const unsigned bin = eu[s] >> 21;
                if (bin > B) {
                    int p = atomicAdd(&ocnt, 1);
                    topv[p] = ev[s];
                    topi[p] = j;
                } else if (bin == B) {
                    int p = atomicAdd(&ccnt, 1);
                    if (p < 512) { cu[p] = eu[s]; cva[p] = ev[s]; cix[p] = j; }
                }
            }
        }
        __syncthreads();
        const int cb = (ccnt < 512) ? ccnt : 512;

        for (int c = tid; c < cb; c += 256) {
            const unsigned u = cu[c];
            const int ix = cix[c];
            int rk = 0;
            for (int c2 = 0; c2 < cb; ++c2) {
                const unsigned u2 = cu[c2];
                rk += (u2 > u) || (u2 == u && cix[c2] < ix);
            }
            if (rk < tn) { topv[m + rk] = cva[c]; topi[m + rk] = ix; }
        }

        // ---------------- fp64 boundary fixup ----------------
        __syncthreads();
        if (tid == 0) {
            float mv = topv[0];
            for (int k = 1; k < KTOP; ++k) mv = fminf(mv, topv[k]);
            svmin = mv;
            ccnt = 0;
            tcnt = 0;
        }
        __syncthreads();
        const float vmin = svmin;
#pragma unroll
        for (int s = 0; s < 8; ++s) {
            const int j = tid + (s << 8);
            if (j < nscan && fabsf(ev[s] - vmin) <= DELTA) {
                int p = atomicAdd(&ccnt, 1);
                if (p < 256) { cva[p] = ev[s]; cix[p] = j; }
            }
        }
        __syncthreads();
        const int mb = ccnt;
        if (mb >= 2 && mb <= 256) {          // block-uniform guard
            if (tid < KTOP && fabsf(topv[tid] - vmin) <= DELTA) {
                int q = atomicAdd(&tcnt, 1);
                spos[q] = tid;
            }
            __syncthreads();
            const int t = tcnt;

            const float* qrow = hs + ((size_t)b * SEQT + i) * DIM;
            for (int c = w; c < mb; c += 4) {
                const float* krow = hs + ((size_t)b * SEQT + cix[c]) * DIM;
                double acc = 0.0;
                for (int d = lane; d < DIM; d += 64)
                    acc += (double)qrow[d] * (double)krow[d];
#pragma unroll
                for (int off = 32; off; off >>= 1) acc += __shfl_xor(acc, off, 64);
                if (lane == 0) dval[c] = acc;
            }
            __syncthreads();

            if (tid < mb) {
                const double dv = dval[tid];
                const int ix = cix[tid];
                int rk = 0;
                for (int c2 = 0; c2 < mb; ++c2)
                    rk += (dval[c2] > dv) || (dval[c2] == dv && cix[c2] < ix);
                if (rk < t) {
                    const int pp = spos[rk];
                    topv[pp] = cva[tid];
                    topi[pp] = ix;
                }
            }
        }
        __syncthreads();
    }

    // ---------------- gather + gate + final write ----------------
    float y0 = 0.f, y1 = 0.f, y2 = 0.f, y3 = 0.f;
#pragma unroll 4
    for (int k = 0; k < KTOP; ++k) {
        const float v = topv[k];             // LDS broadcast
        const int   j = topi[k];
        const uint2 wv = *reinterpret_cast<const uint2*>(hb + (size_t)j * DIM + d0g);
        y0 += v * __uint_as_float(wv.x << 16);
        y1 += v * __uint_as_float(wv.x & 0xffff0000u);
        y2 += v * __uint_as_float(wv.y << 16);
        y3 += v * __uint_as_float(wv.y & 0xffff0000u);
    }

    float p = y0 * ys.x + y1 * ys.y + y2 * ys.z + y3 * ys.w;
#pragma unroll
    for (int off = 32; off; off >>= 1) p += __shfl_xor(p, off, 64);
    if (lane == 0) redg[w] = p;
    __syncthreads();
    if (tid == 0) {
        const float z = redg[0] + redg[1] + redg[2] + redg[3];
        gsh = 1.f / (1.f + __expf(-z));
    }
    __syncthreads();
    const float g = gsh, og = 1.f - g;
    float4 o;
    o.x = g * y0 + og * ys.x;
    o.y = g * y1 + og * ys.y;
    o.z = g * y2 + og * ys.z;
    o.w = g * y3 + og * ys.w;
    *reinterpret_cast<float4*>(iorow + d0g) = o;
}

// ---------------------------------------------------------------------------
extern "C" void kernel_launch(void* const* d_in, const int* in_sizes, int n_in,
                              void* d_out, int out_size, void* d_ws, size_t ws_size,
                              hipStream_t stream) {
    const float* hs = (const float*)d_in[0];
    const float* W  = (const float*)d_in[1];
    float* out = (float*)d_out;

    const size_t Hfull  = (size_t)NB * SEQT * DIM;     // 8388608
    const size_t Hb     = (size_t)SEQT * DIM;          // 2097152
    const size_t Wn     = (size_t)DIM * DIM;           // 1048576
    const size_t SCfull = (size_t)NB * NT2 * 16384;
    const size_t SCb    = (size_t)NT2 * 16384;

    auto need = [&](size_t H, size_t SC) {
        return (2 * H + 2 * Wn) * sizeof(unsigned short) + SC * 4;
    };
    int level = (need(Hfull, SCfull) <= ws_size) ? 1
              : (need(Hfull, SCb) <= ws_size)    ? 2 : 3;

    const size_t H = (level == 3) ? Hb : Hfull;

    unsigned short* hhi  = (unsigned short*)d_ws;
    unsigned short* hlo  = hhi + H;
    unsigned short* wthi = hlo + H;
    unsigned short* wtlo = wthi + Wn;
    float* sc = (float*)(wtlo + Wn);

    wtrans_split<<<dim3(16, 16), dim3(256), 0, stream>>>(W, wthi, wtlo);

    if (level == 1) {
        split_bf16<<<dim3(2048), dim3(256), 0, stream>>>(hs, hhi, hlo, (int)(Hfull / 4));
        const int nbt = NB * NT2;                          // 544 score tiles
        const int nys = ((NB * SEQT) / 128) * (DIM / 128); // 512 ysem tiles
        fused_mfma<<<dim3(nbt + nys), dim3(256), 0, stream>>>(hhi, hlo, wthi, wtlo, sc, out, nbt, 0);
        topk_gather<<<dim3(NB * SEQT), dim3(256), 0, stream>>>(hs, sc, hhi, out, 0, 1);
    } else if (level == 2) {
        split_bf16<<<dim3(2048), dim3(256), 0, stream>>>(hs, hhi, hlo, (int)(Hfull / 4));
        const int nys = ((NB * SEQT) / 128) * (DIM / 128);
        fused_mfma<<<dim3(nys), dim3(256), 0, stream>>>(hhi, hlo, wthi, wtlo, sc, out, 0, 0);
        for (int b = 0; b < NB; ++b) {
            fused_mfma<<<dim3(NT2), dim3(256), 0, stream>>>(hhi, hlo, wthi, wtlo, sc, out, NT2, b);
            topk_gather<<<dim3(SEQT), dim3(256), 0, stream>>>(
                hs, sc, hhi + (size_t)b * Hb, out, b, 0);
        }
    } else {
        for (int b = 0; b < NB; ++b) {
            split_bf16<<<dim3(512), dim3(256), 0, stream>>>(hs + (size_t)b * Hb, hhi, hlo, (int)(Hb / 4));
            fused_mfma<<<dim3(NT2), dim3(256), 0, stream>>>(hhi, hlo, wthi, wtlo, sc, out, NT2, 0);
            fused_mfma<<<dim3((SEQT / 128) * (DIM / 128)), dim3(256), 0, stream>>>(
                hhi, hlo, wthi, wtlo, sc, out + (size_t)b * Hb, 0, 0);
            topk_gather<<<dim3(SEQT), dim3(256), 0, stream>>>(hs, sc, hhi, out, b, 0);
        }
    }
}